// Round 4
// baseline (144.642 us; speedup 1.0000x reference)
//
#include <hip/hip_runtime.h>
#include <hip/hip_bf16.h>
#include <stdint.h>

// DenseConv2d: input (32,128,56,56) f32, weight (256,128,3,3) f32, bias (256) f32
// stride 1, pad 1 -> out (32,256,56,56) f32.
// Implicit GEMM: C[256][100352] = W[256][1152] x im2col[1152][100352], bf16 MFMA.
// Round 4: zero-conflict chunked LDS (pre-permuted gload_lds sources, contiguous
// reads), 64x64 wave tiles (3 waves/SIMD), 3 blocks/CU, 3-deep counted vmcnt,
// L2-resident XCD swizzle, fully unrolled K-loop.

typedef __attribute__((ext_vector_type(8))) short bf16x8;
typedef __attribute__((ext_vector_type(8))) unsigned short ushort8;
typedef __attribute__((ext_vector_type(4))) float f32x4;

#define HW      56
#define SPATIAL 3136        // 56*56
#define C_IN    128
#define K_OUT   256
#define GEMM_K  1152        // 9 * 128, ordered k = tap*128 + c
#define GEMM_N  100352      // 32 * 3136

#define BM 128
#define BN 128
#define BK 32
#define NT 36               // 9 taps * (128/32)
#define BUF_HALVES 8192     // lA 128*32 + lB 128*32 halves (16 KiB)
#define LB_OFF 4096

__device__ __forceinline__ unsigned short f2bf(float f) {
    union { float f; unsigned int u; } v; v.f = f;
    unsigned int u = v.u + 0x7FFFu + ((v.u >> 16) & 1u);   // RTNE
    return (unsigned short)(u >> 16);
}

__device__ __forceinline__ void gload16(const unsigned short* g, unsigned short* l) {
    __builtin_amdgcn_global_load_lds(
        (const __attribute__((address_space(1))) unsigned int*)(g),
        (__attribute__((address_space(3))) unsigned int*)(l),
        16, 0, 0);
}

// weight [256][128][3][3] f32 -> w2 [256][9][128] bf16  (k_out, tap, c)
__global__ void wtrans_kernel(const float* __restrict__ w, unsigned short* __restrict__ w2) {
    int idx = blockIdx.x * 256 + threadIdx.x;       // 294912 total
    int ko  = idx / GEMM_K;
    int r   = idx % GEMM_K;
    int tap = r >> 7;
    int c   = r & 127;
    w2[idx] = f2bf(w[(ko * C_IN + c) * 9 + tap]);
}

// input [32][128][56][56] f32 -> nhwc [32][56][56][128] bf16
__global__ __launch_bounds__(256)
void intrans_kernel(const float* __restrict__ in, unsigned short* __restrict__ nhwc) {
    __shared__ __attribute__((aligned(16))) unsigned short l[56 * 140];
    const int bx = blockIdx.x;                      // 32*56 = 1792
    const int n = bx / HW, h = bx % HW;
    const int tid = threadIdx.x;
    const float* src = in + (size_t)n * C_IN * SPATIAL + h * HW;
    #pragma unroll
    for (int i = 0; i < 28; ++i) {                  // 7168 = 28*256
        int idx = i * 256 + tid;
        int c = idx / HW, w = idx % HW;
        l[w * 140 + c] = f2bf(src[(size_t)c * SPATIAL + w]);
    }
    __syncthreads();
    unsigned short* dst = nhwc + ((size_t)(n * HW + h) * HW) * C_IN;
    #pragma unroll
    for (int j = 0; j < 4; ++j) {
        int chunk = j * 256 + tid;                  // 896 = 56*16 chunks of 8
        if (chunk < 896) {
            int w = chunk >> 4, c8 = chunk & 15;
            *reinterpret_cast<ushort8*>(dst + w * C_IN + c8 * 8) =
                *reinterpret_cast<const ushort8*>(&l[w * 140 + c8 * 8]);
        }
    }
}

// ---------------- main kernel ----------------
// LDS chunk layout: each 16(rows/cols) x 32(k) bf16 subtile is one 1 KiB chunk;
// phys 16B slot s within chunk holds (row = s&15, k-granule = s>>4).
// Staging lane l fetches (row l&15, granule l>>4) -> gload_lds linear dest.
// Compute lane l reads chunk_base + l*16B -> contiguous, zero bank conflicts.
__global__ __launch_bounds__(256, 3)
void conv_mfma_pipe(const unsigned short* __restrict__ nhwc,
                    const unsigned short* __restrict__ w2,
                    const unsigned short* __restrict__ zbuf,
                    const float* __restrict__ bias,
                    float* __restrict__ out) {
    __shared__ __attribute__((aligned(16))) unsigned short lds[3 * BUF_HALVES]; // 48 KiB

    const int tid  = threadIdx.x;
    const int wave = tid >> 6;
    const int lane = tid & 63;
    const int la   = lane & 15;
    const int lkh  = lane >> 4;
    const int gq   = lkh * 8;          // k-granule offset (halves)

    // bijective XCD swizzle: 1568 blocks, 1568 % 8 == 0; within an XCD,
    // alternate m-tiles over a 98-n-tile range -> B-panel ~3.3 MB, L2-resident.
    const int bid = blockIdx.x;
    const int swz = (bid & 7) * 196 + (bid >> 3);
    const int m0  = (swz & 1) * BM;
    const int g0  = (swz >> 1) * BN;

    const int wr = wave >> 1, wc = wave & 1;   // 2x2 wave grid, 64x64 tiles

    // ---- pre-permuted staging descriptors ----
    // A: issue (ja, wave) covers chunk = ja*4+wave (rows chunk*16..+15)
    const unsigned short* wsrc[2];
    #pragma unroll
    for (int ja = 0; ja < 2; ++ja)
        wsrc[ja] = w2 + (size_t)(m0 + (ja * 4 + wave) * 16 + la) * GEMM_K + gq;
    // B: issue (jb, wave) covers chunk = jb*4+wave (cols chunk*16..+15)
    int ohs[2], ows[2], pb[2];
    #pragma unroll
    for (int jb = 0; jb < 2; ++jb) {
        int col  = g0 + (jb * 4 + wave) * 16 + la;
        int nimg = col / SPATIAL;
        int pos  = col - nimg * SPATIAL;
        int oh   = pos / HW;
        int ow   = pos - oh * HW;
        ohs[jb] = oh; ows[jb] = ow;
        pb[jb]  = ((nimg * HW + oh) * HW + ow) * C_IN;
    }

    f32x4 acc[4][4];
    #pragma unroll
    for (int i = 0; i < 4; ++i)
        #pragma unroll
        for (int j = 0; j < 4; ++j)
            acc[i][j] = (f32x4){0.f, 0.f, 0.f, 0.f};

    auto STAGE = [&](int s, int bufi) {
        const int tap = s >> 2, ci = (s & 3) * 32;
        const int dr = tap / 3 - 1, dsx = tap % 3 - 1;
        unsigned short* bA = &lds[bufi * BUF_HALVES];
        unsigned short* bB = bA + LB_OFF;
        const int wofs = tap * C_IN + ci;
        #pragma unroll
        for (int ja = 0; ja < 2; ++ja)
            gload16(wsrc[ja] + wofs, bA + (ja * 4 + wave) * 512);
        const int doff = (dr * HW + dsx) * C_IN + ci + gq;
        #pragma unroll
        for (int jb = 0; jb < 2; ++jb) {
            const int ih = ohs[jb] + dr, iw = ows[jb] + dsx;
            const bool valid = ((unsigned)ih < HW) && ((unsigned)iw < HW);
            const unsigned short* src = valid ? nhwc + pb[jb] + doff : zbuf + gq;
            gload16(src, bB + (jb * 4 + wave) * 512);
        }
    };

    // prologue: 3 stages in flight (12 loads)
    STAGE(0, 0); STAGE(1, 1); STAGE(2, 2);

    #pragma unroll
    for (int t = 0; t < NT; ++t) {
        // 4 loads/stage; keep 2 newer stages (8 loads) in flight
        if (t < NT - 2)       asm volatile("s_waitcnt vmcnt(8)" ::: "memory");
        else if (t == NT - 2) asm volatile("s_waitcnt vmcnt(4)" ::: "memory");
        else                  asm volatile("s_waitcnt vmcnt(0)" ::: "memory");
        __builtin_amdgcn_s_barrier();
        asm volatile("" ::: "memory");

        const int cur = t % 3;
        const unsigned short* A = &lds[cur * BUF_HALVES];
        const unsigned short* B = A + LB_OFF;
        bf16x8 af[4], bv[4];
        #pragma unroll
        for (int mi = 0; mi < 4; ++mi)
            af[mi] = *reinterpret_cast<const bf16x8*>(&A[((wr * 4 + mi) * 64 + lane) * 8]);
        #pragma unroll
        for (int nj = 0; nj < 4; ++nj)
            bv[nj] = *reinterpret_cast<const bf16x8*>(&B[((wc * 4 + nj) * 64 + lane) * 8]);

        __builtin_amdgcn_s_setprio(1);
        #pragma unroll
        for (int mi = 0; mi < 4; ++mi)
            #pragma unroll
            for (int nj = 0; nj < 4; ++nj)
                acc[mi][nj] = __builtin_amdgcn_mfma_f32_16x16x32_bf16(
                    af[mi], bv[nj], acc[mi][nj], 0, 0, 0);
        __builtin_amdgcn_s_setprio(0);

        __builtin_amdgcn_s_barrier();
        asm volatile("" ::: "memory");

        if (t < NT - 3) STAGE(t + 3, cur);
    }

    // ---- epilogue: D col = lane&15, row = (lane>>4)*4 + reg ----
    const int mb = m0 + wr * 64;
    const int cb = g0 + wc * 64;
    #pragma unroll
    for (int mi = 0; mi < 4; ++mi) {
        const f32x4 bv4 = *reinterpret_cast<const f32x4*>(&bias[mb + mi * 16 + lkh * 4]);
        #pragma unroll
        for (int nj = 0; nj < 4; ++nj) {
            const int gcol = cb + nj * 16;          // 16-aligned, no image straddle
            const int n2 = gcol / SPATIAL;
            const int p2 = gcol - n2 * SPATIAL + la;
            float* op = out + ((size_t)(n2 * K_OUT + mb + mi * 16 + lkh * 4)) * SPATIAL + p2;
            op[0]                   = acc[mi][nj][0] + bv4[0];
            op[SPATIAL]             = acc[mi][nj][1] + bv4[1];
            op[2 * SPATIAL]         = acc[mi][nj][2] + bv4[2];
            op[3 * (size_t)SPATIAL] = acc[mi][nj][3] + bv4[3];
        }
    }
}

// ---------------- fallback (round-1 path) if ws is too small ----------------
#define LDK 40
__global__ __launch_bounds__(256)
void conv_mfma_fallback(const float* __restrict__ in,
                        const float* __restrict__ wraw,
                        const float* __restrict__ bias,
                        float* __restrict__ out) {
    __shared__ __attribute__((aligned(16))) unsigned short lA[BM * LDK];
    __shared__ __attribute__((aligned(16))) unsigned short lB[128 * LDK];
    const int tid = threadIdx.x;
    const int m0  = blockIdx.y * BM;
    const int g0  = blockIdx.x * 128;
    const int wave = tid >> 6, lane = tid & 63;
    const int wr = wave >> 1, wc = wave & 1;
    const int la = lane & 15, lkh = lane >> 4, lk = lkh * 8;

    f32x4 acc[4][4];
    #pragma unroll
    for (int i = 0; i < 4; ++i)
        #pragma unroll
        for (int j = 0; j < 4; ++j)
            acc[i][j] = (f32x4){0.f, 0.f, 0.f, 0.f};

    const int jj = tid & 127;
    const int kb = (tid >> 7) * 16;
    const int g = g0 + jj;
    const int nimg = g / SPATIAL;
    const int pos  = g % SPATIAL;
    const int oh = pos / HW, ow = pos % HW;

    for (int tap = 0; tap < 9; ++tap) {
        const int dr = tap / 3 - 1, dsx = tap % 3 - 1;
        const int ih = oh + dr, iw = ow + dsx;
        const bool valid = ((unsigned)ih < HW) && ((unsigned)iw < HW);
        const float* src = in + ((nimg * C_IN) * HW + ih) * HW + iw;
        for (int c0 = 0; c0 < C_IN; c0 += 32) {
            #pragma unroll
            for (int i = 0; i < 2; ++i) {
                const int ch = tid * 2 + i;
                const int row = ch >> 2;
                const int kp = (ch & 3) * 8;
                ushort8 v;
                #pragma unroll
                for (int e = 0; e < 8; ++e)
                    v[e] = f2bf(wraw[((m0 + row) * C_IN + c0 + kp + e) * 9 + tap]);
                *reinterpret_cast<ushort8*>(&lA[row * LDK + kp]) = v;
            }
            {
                ushort8 v0, v1;
                #pragma unroll
                for (int i = 0; i < 8; ++i)
                    v0[i] = f2bf(valid ? src[(c0 + kb + i) * SPATIAL] : 0.f);
                #pragma unroll
                for (int i = 0; i < 8; ++i)
                    v1[i] = f2bf(valid ? src[(c0 + kb + 8 + i) * SPATIAL] : 0.f);
                *reinterpret_cast<ushort8*>(&lB[jj * LDK + kb])     = v0;
                *reinterpret_cast<ushort8*>(&lB[jj * LDK + kb + 8]) = v1;
            }
            __syncthreads();
            bf16x8 af[4], bv[4];
            #pragma unroll
            for (int f = 0; f < 4; ++f) {
                af[f] = *reinterpret_cast<const bf16x8*>(&lA[(wr * 64 + f * 16 + la) * LDK + lk]);
                bv[f] = *reinterpret_cast<const bf16x8*>(&lB[(wc * 64 + f * 16 + la) * LDK + lk]);
            }
            #pragma unroll
            for (int fi = 0; fi < 4; ++fi)
                #pragma unroll
                for (int fj = 0; fj < 4; ++fj)
                    acc[fi][fj] = __builtin_amdgcn_mfma_f32_16x16x32_bf16(
                        af[fi], bv[fj], acc[fi][fj], 0, 0, 0);
            __syncthreads();
        }
    }
    const int mbase = m0 + wr * 64;
    const int cbase = g0 + wc * 64;
    #pragma unroll
    for (int fi = 0; fi < 4; ++fi) {
        float bvv[4];
        #pragma unroll
        for (int r = 0; r < 4; ++r)
            bvv[r] = bias[mbase + fi * 16 + lkh * 4 + r];
        #pragma unroll
        for (int fj = 0; fj < 4; ++fj) {
            const int gcol = cbase + fj * 16 + la;
            const int n2 = gcol / SPATIAL;
            const int p2 = gcol % SPATIAL;
            float* op = out + (size_t)(n2 * K_OUT) * SPATIAL + p2;
            #pragma unroll
            for (int r = 0; r < 4; ++r)
                op[(size_t)(mbase + fi * 16 + lkh * 4 + r) * SPATIAL] = acc[fi][fj][r] + bvv[r];
        }
    }
}

extern "C" void kernel_launch(void* const* d_in, const int* in_sizes, int n_in,
                              void* d_out, int out_size, void* d_ws, size_t ws_size,
                              hipStream_t stream) {
    const float* in   = (const float*)d_in[0];
    const float* w    = (const float*)d_in[1];
    const float* bias = (const float*)d_in[2];
    float* out = (float*)d_out;

    // ws layout (halves): w2 [294912] | nhwc [12845056] | zbuf [64]
    const size_t need_bytes = (294912ull + 12845056ull + 64ull) * 2ull;

    if (ws_size >= need_bytes) {
        unsigned short* w2   = (unsigned short*)d_ws;
        unsigned short* nhwc = w2 + 294912;
        unsigned short* zbuf = nhwc + 12845056;
        wtrans_kernel<<<(K_OUT * GEMM_K) / 256, 256, 0, stream>>>(w, w2);
        intrans_kernel<<<32 * HW, 256, 0, stream>>>(in, nhwc);
        hipMemsetAsync(zbuf, 0, 128, stream);
        conv_mfma_pipe<<<(GEMM_N / BN) * (K_OUT / BM), 256, 0, stream>>>(nhwc, w2, zbuf, bias, out);
    } else {
        dim3 grid(GEMM_N / 128, K_OUT / BM);
        conv_mfma_fallback<<<grid, 256, 0, stream>>>(in, w, bias, out);
    }
}

// Round 5
// 130.214 us; speedup vs baseline: 1.1108x; 1.1108x over previous
//
#include <hip/hip_runtime.h>
#include <hip/hip_bf16.h>
#include <stdint.h>

// DenseConv2d: input (32,128,56,56) f32, weight (256,128,3,3) f32, bias (256) f32
// stride 1, pad 1 -> out (32,256,56,56) f32.
// Round 5: zero-padded bf16 input slab staged ONCE per 32-ch chunk, 9 taps
// consume from LDS; weights prefetched to registers (no A-LDS, no per-tap
// barriers); 4 barrier-pairs per block; acc 4x7, 2 blocks/CU.

typedef __attribute__((ext_vector_type(8))) short bf16x8;
typedef __attribute__((ext_vector_type(8))) unsigned short ushort8;
typedef __attribute__((ext_vector_type(4))) float f32x4;

#define HW       56
#define SPATIAL  3136
#define C_IN     128
#define K_OUT    256
#define GEMM_K   1152
#define GEMM_N   100352      // 32*3136

#define PHW      58
#define PIMG     3364        // 58*58
#define PADTOT   107648      // 32*3364
#define PADTOT_AL 107656     // +8 positions slack for slab tail

#define BM       128
#define BNP      224         // spatial tile = exactly 4 rows of one image
#define SLAB_POS 352         // 348 used (6 padded rows * 58) + pad
#define SLAB_STRIDE 40       // halves (80 B row): 5 slots/row -> 2-way banks
#define SLAB_HALVES (SLAB_POS * SLAB_STRIDE)   // 14080 halves = 28160 B

__device__ __forceinline__ unsigned short f2bf(float f) {
    union { float f; unsigned int u; } v; v.f = f;
    unsigned int u = v.u + 0x7FFFu + ((v.u >> 16) & 1u);   // RTNE
    return (unsigned short)(u >> 16);
}

// weight [256][128][3][3] f32 -> w2k [256][4cc][9tap][32c] bf16
__global__ void wtrans_kernel(const float* __restrict__ w, unsigned short* __restrict__ w2k) {
    int idx = blockIdx.x * 256 + threadIdx.x;    // 294912
    int ko  = idx / GEMM_K;
    int r   = idx % GEMM_K;
    int cc  = r / 288;
    int tap = (r % 288) / 32;
    int c5  = r & 31;
    w2k[idx] = f2bf(w[(ko * C_IN + cc * 32 + c5) * 9 + tap]);
}

// input [32][128][56][56] f32 -> pad[4cc][32img][58*58][32ch] bf16 (pads pre-zeroed)
__global__ __launch_bounds__(256)
void intrans_kernel(const float* __restrict__ in, unsigned short* __restrict__ pad) {
    __shared__ __attribute__((aligned(16))) unsigned short l[56 * 136];
    const int bx = blockIdx.x;                   // 32*56
    const int n = bx / HW, h = bx % HW;
    const int tid = threadIdx.x;
    const float* src = in + (size_t)n * C_IN * SPATIAL + h * HW;
    #pragma unroll
    for (int i = 0; i < 28; ++i) {               // 7168 = 28*256
        int idx = i * 256 + tid;
        int c = idx / HW, w = idx % HW;
        l[w * 136 + c] = f2bf(src[(size_t)c * SPATIAL + w]);
    }
    __syncthreads();
    const int prow = n * PIMG + (h + 1) * PHW;   // padded row base (col 0 = pad)
    #pragma unroll
    for (int j = 0; j < 4; ++j) {
        int chunk = j * 256 + tid;               // 896 = 56*16 chunks of 8 halves
        if (chunk < 896) {
            int w = chunk >> 4, c8 = chunk & 15;
            int cc = c8 >> 2, sub = c8 & 3;
            unsigned short* dst = pad + (size_t)cc * PADTOT_AL * 32
                                + (size_t)(prow + w + 1) * 32 + sub * 8;
            *reinterpret_cast<ushort8*>(dst) =
                *reinterpret_cast<const ushort8*>(&l[w * 136 + c8 * 8]);
        }
    }
}

// ---------------- main kernel ----------------
__global__ __launch_bounds__(256, 2)
void conv_slab(const unsigned short* __restrict__ pad,   // [4][PADTOT_AL][32]
               const unsigned short* __restrict__ w2k,   // [256][4][9][32]
               const float* __restrict__ bias,
               float* __restrict__ out) {
    __shared__ __attribute__((aligned(16))) unsigned short lds[2 * SLAB_HALVES]; // 56320 B

    const int tid  = threadIdx.x;
    const int wave = tid >> 6;
    const int lane = tid & 63;
    const int la   = lane & 15;
    const int lkh  = lane >> 4;

    // XCD swizzle: 896 blocks = 8 * 112
    const int bid = blockIdx.x;
    const int swz = (bid & 7) * 112 + (bid >> 3);
    const int mt  = swz / 448, nt = swz % 448;
    const int m0  = mt * BM;
    const int n_img = nt / 14, r_blk = nt % 14;
    const int origin = n_img * PIMG + r_blk * 4 * PHW;   // padded slab origin

    const int wr = wave >> 1, wc = wave & 1;   // 2x2 waves: 64 m x 112 n each

    // ---- slab staging descriptors (lane: pos += la, ch granule = lkh) ----
    const unsigned short* sbase = pad + (size_t)(origin + la) * 32 + lkh * 8;
    const int wds = la * SLAB_STRIDE + lkh * 8;          // + (i*4+wave)*640 + buf ofs

    // ---- A pointers (weights -> registers) ----
    const unsigned short* aP[4];
    #pragma unroll
    for (int mi = 0; mi < 4; ++mi)
        aP[mi] = w2k + (size_t)(m0 + wr * 64 + mi * 16 + la) * GEMM_K + lkh * 8;

    // ---- B base byte-offsets per nj ----
    int boff[7];
    #pragma unroll
    for (int nj = 0; nj < 7; ++nj) {
        int p  = wc * 112 + nj * 16 + la;                // 0..223
        int q  = p / 56, ow = p % 56;
        int cl = (q + 1) * PHW + ow + 1;                 // padded center, local rows
        boff[nj] = ((cl - 59) * SLAB_STRIDE + lkh * 8) * 2;
    }

    f32x4 acc[4][7];
    #pragma unroll
    for (int i = 0; i < 4; ++i)
        #pragma unroll
        for (int j = 0; j < 7; ++j)
            acc[i][j] = (f32x4){0.f, 0.f, 0.f, 0.f};

    ushort8 sreg[6];      // slab staging registers
    bf16x8  aA[3][4];     // 3-slot rotating weight prefetch

#define LOADSLAB(cc_) do {                                                   \
    _Pragma("unroll")                                                        \
    for (int i = 0; i < 6; ++i)                                              \
        if (i < 5 || wave < 2)                                               \
            sreg[i] = *reinterpret_cast<const ushort8*>(                     \
                sbase + (size_t)(cc_) * PADTOT_AL * 32 + (i * 4 + wave) * 512); \
} while (0)

#define WRITESLAB(buf_) do {                                                 \
    _Pragma("unroll")                                                        \
    for (int i = 0; i < 6; ++i)                                              \
        if (i < 5 || wave < 2)                                               \
            *reinterpret_cast<ushort8*>(                                     \
                &lds[(buf_) * SLAB_HALVES + (i * 4 + wave) * 640 + wds]) = sreg[i]; \
} while (0)

    // prologue
    LOADSLAB(0);
    WRITESLAB(0);
    LOADSLAB(1);
    #pragma unroll
    for (int mi = 0; mi < 4; ++mi) {
        aA[0][mi] = *reinterpret_cast<const bf16x8*>(aP[mi]);
        aA[1][mi] = *reinterpret_cast<const bf16x8*>(aP[mi] + 32);
    }
    __syncthreads();

    #pragma unroll
    for (int cc = 0; cc < 4; ++cc) {
        #pragma unroll
        for (int tap = 0; tap < 9; ++tap) {
            const int tt = cc * 9 + tap;
            // prefetch A(tt+2) into rotating slot (no WAR with aA[tt%3])
            if (tt + 2 < 36) {
                #pragma unroll
                for (int mi = 0; mi < 4; ++mi)
                    aA[(tt + 2) % 3][mi] =
                        *reinterpret_cast<const bf16x8*>(aP[mi] + (tt + 2) * 32);
            }
            const int dr = tap / 3 - 1, dsx = tap % 3 - 1;
            const int IMM = (cc & 1) * (SLAB_HALVES * 2)
                          + ((dr * PHW + dsx) + 59) * (SLAB_STRIDE * 2);
            bf16x8 bv[7];
            #pragma unroll
            for (int nj = 0; nj < 7; ++nj)
                bv[nj] = *reinterpret_cast<const bf16x8*>(
                    reinterpret_cast<const char*>(lds) + boff[nj] + IMM);

            __builtin_amdgcn_s_setprio(1);
            #pragma unroll
            for (int mi = 0; mi < 4; ++mi)
                #pragma unroll
                for (int nj = 0; nj < 7; ++nj)
                    acc[mi][nj] = __builtin_amdgcn_mfma_f32_16x16x32_bf16(
                        aA[tt % 3][mi], bv[nj], acc[mi][nj], 0, 0, 0);
            __builtin_amdgcn_s_setprio(0);
        }
        if (cc < 3) {
            WRITESLAB((cc + 1) & 1);             // compiler waits sreg's loads
            if (cc < 2) LOADSLAB(cc + 2);
            asm volatile("s_waitcnt lgkmcnt(0)" ::: "memory");
            __builtin_amdgcn_s_barrier();
        }
    }

    // ---- epilogue: D col = lane&15, row = (lane>>4)*4 + reg ----
    const int pbase = r_blk * BNP + wc * 112;
    #pragma unroll
    for (int mi = 0; mi < 4; ++mi) {
        const f32x4 bv4 = *reinterpret_cast<const f32x4*>(
            &bias[m0 + wr * 64 + mi * 16 + lkh * 4]);
        #pragma unroll
        for (int nj = 0; nj < 7; ++nj) {
            const int p2 = pbase + nj * 16 + la;
            float* op = out + ((size_t)(n_img * K_OUT + m0 + wr * 64 + mi * 16 + lkh * 4))
                              * SPATIAL + p2;
            op[0]                   = acc[mi][nj][0] + bv4[0];
            op[SPATIAL]             = acc[mi][nj][1] + bv4[1];
            op[2 * SPATIAL]         = acc[mi][nj][2] + bv4[2];
            op[3 * (size_t)SPATIAL] = acc[mi][nj][3] + bv4[3];
        }
    }
#undef LOADSLAB
#undef WRITESLAB
}

// ---------------- fallback (round-1 path) if ws is too small ----------------
#define LDK 40
__global__ __launch_bounds__(256)
void conv_mfma_fallback(const float* __restrict__ in,
                        const float* __restrict__ wraw,
                        const float* __restrict__ bias,
                        float* __restrict__ out) {
    __shared__ __attribute__((aligned(16))) unsigned short lA[BM * LDK];
    __shared__ __attribute__((aligned(16))) unsigned short lB[128 * LDK];
    const int tid = threadIdx.x;
    const int m0  = blockIdx.y * BM;
    const int g0  = blockIdx.x * 128;
    const int wave = tid >> 6, lane = tid & 63;
    const int wr = wave >> 1, wc = wave & 1;
    const int la = lane & 15, lkh = lane >> 4, lk = lkh * 8;

    f32x4 acc[4][4];
    #pragma unroll
    for (int i = 0; i < 4; ++i)
        #pragma unroll
        for (int j = 0; j < 4; ++j)
            acc[i][j] = (f32x4){0.f, 0.f, 0.f, 0.f};

    const int jj = tid & 127;
    const int kb = (tid >> 7) * 16;
    const int g = g0 + jj;
    const int nimg = g / SPATIAL;
    const int pos  = g % SPATIAL;
    const int oh = pos / HW, ow = pos % HW;

    for (int tap = 0; tap < 9; ++tap) {
        const int dr = tap / 3 - 1, dsx = tap % 3 - 1;
        const int ih = oh + dr, iw = ow + dsx;
        const bool valid = ((unsigned)ih < HW) && ((unsigned)iw < HW);
        const float* src = in + ((nimg * C_IN) * HW + ih) * HW + iw;
        for (int c0 = 0; c0 < C_IN; c0 += 32) {
            #pragma unroll
            for (int i = 0; i < 2; ++i) {
                const int ch = tid * 2 + i;
                const int row = ch >> 2;
                const int kp = (ch & 3) * 8;
                ushort8 v;
                #pragma unroll
                for (int e = 0; e < 8; ++e)
                    v[e] = f2bf(wraw[((m0 + row) * C_IN + c0 + kp + e) * 9 + tap]);
                *reinterpret_cast<ushort8*>(&lA[row * LDK + kp]) = v;
            }
            {
                ushort8 v0, v1;
                #pragma unroll
                for (int i = 0; i < 8; ++i)
                    v0[i] = f2bf(valid ? src[(c0 + kb + i) * SPATIAL] : 0.f);
                #pragma unroll
                for (int i = 0; i < 8; ++i)
                    v1[i] = f2bf(valid ? src[(c0 + kb + 8 + i) * SPATIAL] : 0.f);
                *reinterpret_cast<ushort8*>(&lB[jj * LDK + kb])     = v0;
                *reinterpret_cast<ushort8*>(&lB[jj * LDK + kb + 8]) = v1;
            }
            __syncthreads();
            bf16x8 af[4], bv[4];
            #pragma unroll
            for (int f = 0; f < 4; ++f) {
                af[f] = *reinterpret_cast<const bf16x8*>(&lA[(wr * 64 + f * 16 + la) * LDK + lk]);
                bv[f] = *reinterpret_cast<const bf16x8*>(&lB[(wc * 64 + f * 16 + la) * LDK + lk]);
            }
            #pragma unroll
            for (int fi = 0; fi < 4; ++fi)
                #pragma unroll
                for (int fj = 0; fj < 4; ++fj)
                    acc[fi][fj] = __builtin_amdgcn_mfma_f32_16x16x32_bf16(
                        af[fi], bv[fj], acc[fi][fj], 0, 0, 0);
            __syncthreads();
        }
    }
    const int mbase = m0 + wr * 64;
    const int cbase = g0 + wc * 64;
    #pragma unroll
    for (int fi = 0; fi < 4; ++fi) {
        float bvv[4];
        #pragma unroll
        for (int r = 0; r < 4; ++r)
            bvv[r] = bias[mbase + fi * 16 + lkh * 4 + r];
        #pragma unroll
        for (int fj = 0; fj < 4; ++fj) {
            const int gcol = cbase + fj * 16 + la;
            const int n2 = gcol / SPATIAL;
            const int p2 = gcol % SPATIAL;
            float* op = out + (size_t)(n2 * K_OUT) * SPATIAL + p2;
            #pragma unroll
            for (int r = 0; r < 4; ++r)
                op[(size_t)(mbase + fi * 16 + lkh * 4 + r) * SPATIAL] = acc[fi][fj][r] + bvv[r];
        }
    }
}

extern "C" void kernel_launch(void* const* d_in, const int* in_sizes, int n_in,
                              void* d_out, int out_size, void* d_ws, size_t ws_size,
                              hipStream_t stream) {
    const float* in   = (const float*)d_in[0];
    const float* w    = (const float*)d_in[1];
    const float* bias = (const float*)d_in[2];
    float* out = (float*)d_out;

    // ws layout (halves): pad [4*PADTOT_AL*32] | w2k [294912]
    const size_t pad_halves = 4ull * PADTOT_AL * 32ull;     // 13,779,968
    const size_t need_bytes = (pad_halves + 294912ull) * 2ull;  // ~28.15 MB

    if (ws_size >= need_bytes) {
        unsigned short* pad = (unsigned short*)d_ws;
        unsigned short* w2k = pad + pad_halves;
        hipMemsetAsync(pad, 0, pad_halves * 2ull, stream);
        wtrans_kernel<<<(K_OUT * GEMM_K) / 256, 256, 0, stream>>>(w, w2k);
        intrans_kernel<<<32 * HW, 256, 0, stream>>>(in, pad);
        conv_slab<<<(GEMM_N / BNP) * (K_OUT / BM), 256, 0, stream>>>(pad, w2k, bias, out);
    } else {
        dim3 grid(GEMM_N / 128, K_OUT / BM);
        conv_mfma_fallback<<<grid, 256, 0, stream>>>(in, w, bias, out);
    }
}

// Round 6
// 128.888 us; speedup vs baseline: 1.1222x; 1.0103x over previous
//
#include <hip/hip_runtime.h>
#include <hip/hip_bf16.h>
#include <stdint.h>

// DenseConv2d: input (32,128,56,56) f32, weight (256,128,3,3) f32, bias (256) f32
// stride 1, pad 1 -> out (32,256,56,56) f32.
// Round 6: round-5 slab structure + per-tap barrier phase discipline (T3/T5
// mechanism: anti-phase the 2 resident blocks so LDS bursts overlap MFMA
// bursts), stride-36 conflict-free slab, border-only pad zeroing.

typedef __attribute__((ext_vector_type(8))) short bf16x8;
typedef __attribute__((ext_vector_type(8))) unsigned short ushort8;
typedef __attribute__((ext_vector_type(4))) float f32x4;

#define HW       56
#define SPATIAL  3136
#define C_IN     128
#define K_OUT    256
#define GEMM_K   1152
#define GEMM_N   100352      // 32*3136

#define PHW      58
#define PIMG     3364        // 58*58
#define PADTOT   107648      // 32*3364
#define PADTOT_AL 107656     // +8 positions slack for slab tail

#define BM       128
#define BNP      224         // spatial tile = exactly 4 rows of one image
#define SLAB_POS 352         // 348 used (6 padded rows * 58) + 4 slack
#define SLAB_STRIDE 36       // halves (72 B): banks 18i%32 -> 16 distinct
#define SLAB_HALVES (SLAB_POS * SLAB_STRIDE)   // 12672 halves = 25344 B

__device__ __forceinline__ unsigned short f2bf(float f) {
    union { float f; unsigned int u; } v; v.f = f;
    unsigned int u = v.u + 0x7FFFu + ((v.u >> 16) & 1u);   // RTNE
    return (unsigned short)(u >> 16);
}

// weight [256][128][3][3] f32 -> w2k [256][4cc][9tap][32c] bf16
__global__ void wtrans_kernel(const float* __restrict__ w, unsigned short* __restrict__ w2k) {
    int idx = blockIdx.x * 256 + threadIdx.x;    // 294912
    int ko  = idx / GEMM_K;
    int r   = idx % GEMM_K;
    int cc  = r / 288;
    int tap = (r % 288) / 32;
    int c5  = r & 31;
    w2k[idx] = f2bf(w[(ko * C_IN + cc * 32 + c5) * 9 + tap]);
}

// zero only the border ring of pad[4][32][58*58][32] (1.9 MB, not 27.6 MB)
__global__ __launch_bounds__(256)
void border_zero(unsigned short* __restrict__ pad) {
    int idx = blockIdx.x * 256 + threadIdx.x;    // 4*32*228 = 29184
    if (idx >= 29184) return;
    int cc  = idx / 7296;
    int r   = idx % 7296;
    int img = r / 228;
    int p   = r % 228;
    int pos;
    if (p < 58)       pos = p;                       // top row
    else if (p < 116) pos = 57 * PHW + (p - 58);     // bottom row
    else { int i = p - 116; pos = (1 + (i >> 1)) * PHW + (i & 1) * 57; }
    unsigned short* d = pad + (size_t)cc * PADTOT_AL * 32
                      + ((size_t)img * PIMG + pos) * 32;
    const ushort8 z = (ushort8){0,0,0,0,0,0,0,0};
    *reinterpret_cast<ushort8*>(d)      = z;
    *reinterpret_cast<ushort8*>(d + 8)  = z;
    *reinterpret_cast<ushort8*>(d + 16) = z;
    *reinterpret_cast<ushort8*>(d + 24) = z;
}

// input [32][128][56][56] f32 -> pad[4cc][32img][58*58][32ch] bf16 (interior)
__global__ __launch_bounds__(256)
void intrans_kernel(const float* __restrict__ in, unsigned short* __restrict__ pad) {
    __shared__ __attribute__((aligned(16))) unsigned short l[56 * 136];
    const int bx = blockIdx.x;                   // 32*56
    const int n = bx / HW, h = bx % HW;
    const int tid = threadIdx.x;
    const float* src = in + (size_t)n * C_IN * SPATIAL + h * HW;
    #pragma unroll
    for (int i = 0; i < 28; ++i) {               // 7168 = 28*256
        int idx = i * 256 + tid;
        int c = idx / HW, w = idx % HW;
        l[w * 136 + c] = f2bf(src[(size_t)c * SPATIAL + w]);
    }
    __syncthreads();
    const int prow = n * PIMG + (h + 1) * PHW;
    #pragma unroll
    for (int j = 0; j < 4; ++j) {
        int chunk = j * 256 + tid;               // 896 = 56*16 chunks of 8 halves
        if (chunk < 896) {
            int w = chunk >> 4, c8 = chunk & 15;
            int cc = c8 >> 2, sub = c8 & 3;
            unsigned short* dst = pad + (size_t)cc * PADTOT_AL * 32
                                + (size_t)(prow + w + 1) * 32 + sub * 8;
            *reinterpret_cast<ushort8*>(dst) =
                *reinterpret_cast<const ushort8*>(&l[w * 136 + c8 * 8]);
        }
    }
}

// ---------------- main kernel ----------------
__global__ __launch_bounds__(256, 2)
void conv_slab(const unsigned short* __restrict__ pad,   // [4][PADTOT_AL][32]
               const unsigned short* __restrict__ w2k,   // [256][4][9][32]
               const float* __restrict__ bias,
               float* __restrict__ out) {
    __shared__ __attribute__((aligned(16))) unsigned short lds[2 * SLAB_HALVES]; // 50688 B

    const int tid  = threadIdx.x;
    const int wave = tid >> 6;
    const int lane = tid & 63;
    const int la   = lane & 15;
    const int lkh  = lane >> 4;

    // XCD swizzle: 896 blocks = 8 * 112
    const int bid = blockIdx.x;
    const int swz = (bid & 7) * 112 + (bid >> 3);
    const int mt  = swz / 448, nt = swz % 448;
    const int m0  = mt * BM;
    const int n_img = nt / 14, r_blk = nt % 14;
    const int origin = n_img * PIMG + r_blk * 4 * PHW;

    const int wr = wave >> 1, wc = wave & 1;   // 2x2 waves: 64 m x 112 n each

    // ---- slab staging descriptors (lane: pos += la, ch granule = lkh) ----
    const unsigned short* sbase = pad + (size_t)(origin + la) * 32 + lkh * 8;
    const int wds = la * SLAB_STRIDE + lkh * 8;

    // ---- A pointers (weights -> registers) ----
    const unsigned short* aP[4];
    #pragma unroll
    for (int mi = 0; mi < 4; ++mi)
        aP[mi] = w2k + (size_t)(m0 + wr * 64 + mi * 16 + la) * GEMM_K + lkh * 8;

    // ---- B base byte-offsets per nj ----
    int boff[7];
    #pragma unroll
    for (int nj = 0; nj < 7; ++nj) {
        int p  = wc * 112 + nj * 16 + la;                // 0..223
        int q  = p / 56, ow = p % 56;
        int cl = (q + 1) * PHW + ow + 1;                 // padded center row/col
        boff[nj] = ((cl - 59) * SLAB_STRIDE + lkh * 8) * 2;
    }

    f32x4 acc[4][7];
    #pragma unroll
    for (int i = 0; i < 4; ++i)
        #pragma unroll
        for (int j = 0; j < 7; ++j)
            acc[i][j] = (f32x4){0.f, 0.f, 0.f, 0.f};

    ushort8 sreg[6];      // slab staging registers
    bf16x8  aA[3][4];     // 3-slot rotating weight prefetch

#define LOADSLAB(cc_) do {                                                   \
    _Pragma("unroll")                                                        \
    for (int i = 0; i < 6; ++i)                                              \
        if (i < 5 || wave < 2)                                               \
            sreg[i] = *reinterpret_cast<const ushort8*>(                     \
                sbase + (size_t)(cc_) * PADTOT_AL * 32 + (i * 4 + wave) * 512); \
} while (0)

#define WRITESLAB(buf_) do {                                                 \
    _Pragma("unroll")                                                        \
    for (int i = 0; i < 6; ++i)                                              \
        if (i < 5 || wave < 2)                                               \
            *reinterpret_cast<ushort8*>(                                     \
                &lds[(buf_) * SLAB_HALVES + (i * 4 + wave) * (16 * SLAB_STRIDE) + wds]) = sreg[i]; \
} while (0)

    // prologue
    LOADSLAB(0);
    WRITESLAB(0);
    LOADSLAB(1);
    #pragma unroll
    for (int mi = 0; mi < 4; ++mi) {
        aA[0][mi] = *reinterpret_cast<const bf16x8*>(aP[mi]);
        aA[1][mi] = *reinterpret_cast<const bf16x8*>(aP[mi] + 32);
    }
    __syncthreads();

    #pragma unroll
    for (int cc = 0; cc < 4; ++cc) {
        #pragma unroll
        for (int tap = 0; tap < 9; ++tap) {
            const int tt = cc * 9 + tap;
            // A prefetch (tt+2), longest latency first; floats across barriers
            if (tt + 2 < 36) {
                #pragma unroll
                for (int mi = 0; mi < 4; ++mi)
                    aA[(tt + 2) % 3][mi] =
                        *reinterpret_cast<const bf16x8*>(aP[mi] + (tt + 2) * 32);
            }
            const int dr = tap / 3 - 1, dsx = tap % 3 - 1;
            const int IMM = (cc & 1) * (SLAB_HALVES * 2)
                          + ((dr * PHW + dsx) + 59) * (SLAB_STRIDE * 2);
            bf16x8 bv[7];
            #pragma unroll
            for (int nj = 0; nj < 7; ++nj)
                bv[nj] = *reinterpret_cast<const bf16x8*>(
                    reinterpret_cast<const char*>(lds) + boff[nj] + IMM);

            // phase barrier: align waves so LDS-drain and MFMA bursts anti-phase
            __builtin_amdgcn_s_barrier();
            __builtin_amdgcn_sched_barrier(0);

            __builtin_amdgcn_s_setprio(1);
            #pragma unroll
            for (int mi = 0; mi < 4; ++mi)
                #pragma unroll
                for (int nj = 0; nj < 7; ++nj)
                    acc[mi][nj] = __builtin_amdgcn_mfma_f32_16x16x32_bf16(
                        aA[tt % 3][mi], bv[nj], acc[mi][nj], 0, 0, 0);
            __builtin_amdgcn_s_setprio(0);

            __builtin_amdgcn_sched_barrier(0);
            __builtin_amdgcn_s_barrier();
        }
        if (cc < 3) {
            WRITESLAB((cc + 1) & 1);             // compiler waits sreg's loads
            if (cc < 2) LOADSLAB(cc + 2);
            asm volatile("s_waitcnt lgkmcnt(0)" ::: "memory");
            __builtin_amdgcn_s_barrier();
        }
    }

    // ---- epilogue: D col = lane&15, row = (lane>>4)*4 + reg ----
    const int pbase = r_blk * BNP + wc * 112;
    #pragma unroll
    for (int mi = 0; mi < 4; ++mi) {
        const f32x4 bv4 = *reinterpret_cast<const f32x4*>(
            &bias[m0 + wr * 64 + mi * 16 + lkh * 4]);
        #pragma unroll
        for (int nj = 0; nj < 7; ++nj) {
            const int p2 = pbase + nj * 16 + la;
            float* op = out + ((size_t)(n_img * K_OUT + m0 + wr * 64 + mi * 16 + lkh * 4))
                              * SPATIAL + p2;
            op[0]                   = acc[mi][nj][0] + bv4[0];
            op[SPATIAL]             = acc[mi][nj][1] + bv4[1];
            op[2 * SPATIAL]         = acc[mi][nj][2] + bv4[2];
            op[3 * (size_t)SPATIAL] = acc[mi][nj][3] + bv4[3];
        }
    }
#undef LOADSLAB
#undef WRITESLAB
}

// ---------------- fallback (round-1 path) if ws is too small ----------------
#define LDK 40
__global__ __launch_bounds__(256)
void conv_mfma_fallback(const float* __restrict__ in,
                        const float* __restrict__ wraw,
                        const float* __restrict__ bias,
                        float* __restrict__ out) {
    __shared__ __attribute__((aligned(16))) unsigned short lA[BM * LDK];
    __shared__ __attribute__((aligned(16))) unsigned short lB[128 * LDK];
    const int tid = threadIdx.x;
    const int m0  = blockIdx.y * BM;
    const int g0  = blockIdx.x * 128;
    const int wave = tid >> 6, lane = tid & 63;
    const int wr = wave >> 1, wc = wave & 1;
    const int la = lane & 15, lkh = lane >> 4, lk = lkh * 8;

    f32x4 acc[4][4];
    #pragma unroll
    for (int i = 0; i < 4; ++i)
        #pragma unroll
        for (int j = 0; j < 4; ++j)
            acc[i][j] = (f32x4){0.f, 0.f, 0.f, 0.f};

    const int jj = tid & 127;
    const int kb = (tid >> 7) * 16;
    const int g = g0 + jj;
    const int nimg = g / SPATIAL;
    const int pos  = g % SPATIAL;
    const int oh = pos / HW, ow = pos % HW;

    for (int tap = 0; tap < 9; ++tap) {
        const int dr = tap / 3 - 1, dsx = tap % 3 - 1;
        const int ih = oh + dr, iw = ow + dsx;
        const bool valid = ((unsigned)ih < HW) && ((unsigned)iw < HW);
        const float* src = in + ((nimg * C_IN) * HW + ih) * HW + iw;
        for (int c0 = 0; c0 < C_IN; c0 += 32) {
            #pragma unroll
            for (int i = 0; i < 2; ++i) {
                const int ch = tid * 2 + i;
                const int row = ch >> 2;
                const int kp = (ch & 3) * 8;
                ushort8 v;
                #pragma unroll
                for (int e = 0; e < 8; ++e)
                    v[e] = f2bf(wraw[((m0 + row) * C_IN + c0 + kp + e) * 9 + tap]);
                *reinterpret_cast<ushort8*>(&lA[row * LDK + kp]) = v;
            }
            {
                ushort8 v0, v1;
                #pragma unroll
                for (int i = 0; i < 8; ++i)
                    v0[i] = f2bf(valid ? src[(c0 + kb + i) * SPATIAL] : 0.f);
                #pragma unroll
                for (int i = 0; i < 8; ++i)
                    v1[i] = f2bf(valid ? src[(c0 + kb + 8 + i) * SPATIAL] : 0.f);
                *reinterpret_cast<ushort8*>(&lB[jj * LDK + kb])     = v0;
                *reinterpret_cast<ushort8*>(&lB[jj * LDK + kb + 8]) = v1;
            }
            __syncthreads();
            bf16x8 af[4], bv[4];
            #pragma unroll
            for (int f = 0; f < 4; ++f) {
                af[f] = *reinterpret_cast<const bf16x8*>(&lA[(wr * 64 + f * 16 + la) * LDK + lk]);
                bv[f] = *reinterpret_cast<const bf16x8*>(&lB[(wc * 64 + f * 16 + la) * LDK + lk]);
            }
            #pragma unroll
            for (int fi = 0; fi < 4; ++fi)
                #pragma unroll
                for (int fj = 0; fj < 4; ++fj)
                    acc[fi][fj] = __builtin_amdgcn_mfma_f32_16x16x32_bf16(
                        af[fi], bv[fj], acc[fi][fj], 0, 0, 0);
            __syncthreads();
        }
    }
    const int mbase = m0 + wr * 64;
    const int cbase = g0 + wc * 64;
    #pragma unroll
    for (int fi = 0; fi < 4; ++fi) {
        float bvv[4];
        #pragma unroll
        for (int r = 0; r < 4; ++r)
            bvv[r] = bias[mbase + fi * 16 + lkh * 4 + r];
        #pragma unroll
        for (int fj = 0; fj < 4; ++fj) {
            const int gcol = cbase + fj * 16 + la;
            const int n2 = gcol / SPATIAL;
            const int p2 = gcol % SPATIAL;
            float* op = out + (size_t)(n2 * K_OUT) * SPATIAL + p2;
            #pragma unroll
            for (int r = 0; r < 4; ++r)
                op[(size_t)(mbase + fi * 16 + lkh * 4 + r) * SPATIAL] = acc[fi][fj][r] + bvv[r];
        }
    }
}

extern "C" void kernel_launch(void* const* d_in, const int* in_sizes, int n_in,
                              void* d_out, int out_size, void* d_ws, size_t ws_size,
                              hipStream_t stream) {
    const float* in   = (const float*)d_in[0];
    const float* w    = (const float*)d_in[1];
    const float* bias = (const float*)d_in[2];
    float* out = (float*)d_out;

    // ws layout (halves): pad [4*PADTOT_AL*32] | w2k [294912]
    const size_t pad_halves = 4ull * PADTOT_AL * 32ull;     // 13,779,968
    const size_t need_bytes = (pad_halves + 294912ull) * 2ull;  // ~28.15 MB

    if (ws_size >= need_bytes) {
        unsigned short* pad = (unsigned short*)d_ws;
        unsigned short* w2k = pad + pad_halves;
        border_zero<<<114, 256, 0, stream>>>(pad);
        wtrans_kernel<<<(K_OUT * GEMM_K) / 256, 256, 0, stream>>>(w, w2k);
        intrans_kernel<<<32 * HW, 256, 0, stream>>>(in, pad);
        conv_slab<<<(GEMM_N / BNP) * (K_OUT / BM), 256, 0, stream>>>(pad, w2k, bias, out);
    } else {
        dim3 grid(GEMM_N / 128, K_OUT / BM);
        conv_mfma_fallback<<<grid, 256, 0, stream>>>(in, w, bias, out);
    }
}

// Round 7
// 125.731 us; speedup vs baseline: 1.1504x; 1.0251x over previous
//
#include <hip/hip_runtime.h>
#include <hip/hip_bf16.h>
#include <stdint.h>

// DenseConv2d: input (32,128,56,56) f32, weight (256,128,3,3) f32, bias (256) f32
// stride 1, pad 1 -> out (32,256,56,56) f32.
// Round 7: intra-wave software pipeline — double-buffered B fragments read one
// tap ahead (breaks the per-tap ds_read->wait->MFMA serial chain), A prefetch
// depth 2, per-tap barriers removed (round 6 proved them useless).

typedef __attribute__((ext_vector_type(8))) short bf16x8;
typedef __attribute__((ext_vector_type(8))) unsigned short ushort8;
typedef __attribute__((ext_vector_type(4))) float f32x4;

#define HW       56
#define SPATIAL  3136
#define C_IN     128
#define K_OUT    256
#define GEMM_K   1152
#define GEMM_N   100352      // 32*3136

#define PHW      58
#define PIMG     3364        // 58*58
#define PADTOT_AL 107656     // 32*3364 + 8 slack positions

#define BM       128
#define BNP      224         // spatial tile = exactly 4 rows of one image
#define SLAB_POS 352         // 348 used (6 padded rows * 58) + 4 slack
#define SLAB_STRIDE 36       // halves (72 B): banks 18i%32 -> 16 distinct evens
#define SLAB_HALVES (SLAB_POS * SLAB_STRIDE)   // 12672 halves = 25344 B

__device__ __forceinline__ unsigned short f2bf(float f) {
    union { float f; unsigned int u; } v; v.f = f;
    unsigned int u = v.u + 0x7FFFu + ((v.u >> 16) & 1u);   // RTNE
    return (unsigned short)(u >> 16);
}

// weight [256][128][3][3] f32 -> w2k [256][4cc][9tap][32c] bf16
__global__ void wtrans_kernel(const float* __restrict__ w, unsigned short* __restrict__ w2k) {
    int idx = blockIdx.x * 256 + threadIdx.x;    // 294912
    int ko  = idx / GEMM_K;
    int r   = idx % GEMM_K;
    int cc  = r / 288;
    int tap = (r % 288) / 32;
    int c5  = r & 31;
    w2k[idx] = f2bf(w[(ko * C_IN + cc * 32 + c5) * 9 + tap]);
}

// zero only the border ring of pad[4][32][58*58][32] (1.9 MB, not 27.6 MB)
__global__ __launch_bounds__(256)
void border_zero(unsigned short* __restrict__ pad) {
    int idx = blockIdx.x * 256 + threadIdx.x;    // 4*32*228 = 29184
    if (idx >= 29184) return;
    int cc  = idx / 7296;
    int r   = idx % 7296;
    int img = r / 228;
    int p   = r % 228;
    int pos;
    if (p < 58)       pos = p;                       // top row
    else if (p < 116) pos = 57 * PHW + (p - 58);     // bottom row
    else { int i = p - 116; pos = (1 + (i >> 1)) * PHW + (i & 1) * 57; }
    unsigned short* d = pad + (size_t)cc * PADTOT_AL * 32
                      + ((size_t)img * PIMG + pos) * 32;
    const ushort8 z = (ushort8){0,0,0,0,0,0,0,0};
    *reinterpret_cast<ushort8*>(d)      = z;
    *reinterpret_cast<ushort8*>(d + 8)  = z;
    *reinterpret_cast<ushort8*>(d + 16) = z;
    *reinterpret_cast<ushort8*>(d + 24) = z;
}

// input [32][128][56][56] f32 -> pad[4cc][32img][58*58][32ch] bf16 (interior)
__global__ __launch_bounds__(256)
void intrans_kernel(const float* __restrict__ in, unsigned short* __restrict__ pad) {
    __shared__ __attribute__((aligned(16))) unsigned short l[56 * 136];
    const int bx = blockIdx.x;                   // 32*56
    const int n = bx / HW, h = bx % HW;
    const int tid = threadIdx.x;
    const float* src = in + (size_t)n * C_IN * SPATIAL + h * HW;
    #pragma unroll
    for (int i = 0; i < 28; ++i) {               // 7168 = 28*256
        int idx = i * 256 + tid;
        int c = idx / HW, w = idx % HW;
        l[w * 136 + c] = f2bf(src[(size_t)c * SPATIAL + w]);
    }
    __syncthreads();
    const int prow = n * PIMG + (h + 1) * PHW;
    #pragma unroll
    for (int j = 0; j < 4; ++j) {
        int chunk = j * 256 + tid;               // 896 = 56*16 chunks of 8 halves
        if (chunk < 896) {
            int w = chunk >> 4, c8 = chunk & 15;
            int cc = c8 >> 2, sub = c8 & 3;
            unsigned short* dst = pad + (size_t)cc * PADTOT_AL * 32
                                + (size_t)(prow + w + 1) * 32 + sub * 8;
            *reinterpret_cast<ushort8*>(dst) =
                *reinterpret_cast<const ushort8*>(&l[w * 136 + c8 * 8]);
        }
    }
}

// ---------------- main kernel ----------------
__global__ __launch_bounds__(256, 2)
void conv_slab(const unsigned short* __restrict__ pad,   // [4][PADTOT_AL][32]
               const unsigned short* __restrict__ w2k,   // [256][4][9][32]
               const float* __restrict__ bias,
               float* __restrict__ out) {
    __shared__ __attribute__((aligned(16))) unsigned short lds[2 * SLAB_HALVES]; // 50688 B

    const int tid  = threadIdx.x;
    const int wave = tid >> 6;
    const int lane = tid & 63;
    const int la   = lane & 15;
    const int lkh  = lane >> 4;

    // XCD swizzle: 896 blocks = 8 * 112
    const int bid = blockIdx.x;
    const int swz = (bid & 7) * 112 + (bid >> 3);
    const int mt  = swz / 448, nt = swz % 448;
    const int m0  = mt * BM;
    const int n_img = nt / 14, r_blk = nt % 14;
    const int origin = n_img * PIMG + r_blk * 4 * PHW;

    const int wr = wave >> 1, wc = wave & 1;   // 2x2 waves: 64 m x 112 n each

    // ---- slab staging descriptors (lane: pos += la, ch granule = lkh) ----
    const unsigned short* sbase = pad + (size_t)(origin + la) * 32 + lkh * 8;
    const int wds = la * SLAB_STRIDE + lkh * 8;

    // ---- A pointers (weights -> registers) ----
    const unsigned short* aP[4];
    #pragma unroll
    for (int mi = 0; mi < 4; ++mi)
        aP[mi] = w2k + (size_t)(m0 + wr * 64 + mi * 16 + la) * GEMM_K + lkh * 8;

    // ---- B base byte-offsets per nj ----
    int boff[7];
    #pragma unroll
    for (int nj = 0; nj < 7; ++nj) {
        int p  = wc * 112 + nj * 16 + la;                // 0..223
        int q  = p / 56, ow = p % 56;
        int cl = (q + 1) * PHW + ow + 1;                 // padded center row/col
        boff[nj] = ((cl - 59) * SLAB_STRIDE + lkh * 8) * 2;
    }

    f32x4 acc[4][7];
    #pragma unroll
    for (int i = 0; i < 4; ++i)
        #pragma unroll
        for (int j = 0; j < 7; ++j)
            acc[i][j] = (f32x4){0.f, 0.f, 0.f, 0.f};

    ushort8 sreg[6];      // slab staging registers
    bf16x8  aA[2][4];     // 2-slot rotating weight prefetch (1 tap ahead)
    bf16x8  bvb[2][7];    // double-buffered B fragments (1 tap ahead)

#define LOADSLAB(cc_) do {                                                   \
    _Pragma("unroll")                                                        \
    for (int i = 0; i < 6; ++i)                                              \
        if (i < 5 || wave < 2)                                               \
            sreg[i] = *reinterpret_cast<const ushort8*>(                     \
                sbase + (size_t)(cc_) * PADTOT_AL * 32 + (i * 4 + wave) * 512); \
} while (0)

#define WRITESLAB(buf_) do {                                                 \
    _Pragma("unroll")                                                        \
    for (int i = 0; i < 6; ++i)                                              \
        if (i < 5 || wave < 2)                                               \
            *reinterpret_cast<ushort8*>(                                     \
                &lds[(buf_) * SLAB_HALVES + (i * 4 + wave) * (16 * SLAB_STRIDE) + wds]) = sreg[i]; \
} while (0)

// read the 7 B fragments of (ccq, tapq) into dst[0..6]
#define READBV(dst, ccq, tapq) do {                                          \
    const int IMM_ = ((ccq) & 1) * (SLAB_HALVES * 2)                         \
                   + ((((tapq) / 3 - 1) * PHW + ((tapq) % 3 - 1)) + 59)      \
                     * (SLAB_STRIDE * 2);                                    \
    _Pragma("unroll")                                                        \
    for (int nj = 0; nj < 7; ++nj)                                           \
        (dst)[nj] = *reinterpret_cast<const bf16x8*>(                        \
            reinterpret_cast<const char*>(lds) + boff[nj] + IMM_);           \
} while (0)

    // prologue
    LOADSLAB(0);
    WRITESLAB(0);
    LOADSLAB(1);
    #pragma unroll
    for (int mi = 0; mi < 4; ++mi)
        aA[0][mi] = *reinterpret_cast<const bf16x8*>(aP[mi]);   // tap tt=0
    __syncthreads();
    READBV(bvb[0], 0, 0);                                       // prefill tt=0

    #pragma unroll
    for (int cc = 0; cc < 4; ++cc) {
        #pragma unroll
        for (int tap = 0; tap < 9; ++tap) {
            const int tt = cc * 9 + tap;
            // A prefetch for tt+1 (consumed next tap; ~543cy slack > L2 lat)
            if (tt + 1 < 36) {
                #pragma unroll
                for (int mi = 0; mi < 4; ++mi)
                    aA[(tt + 1) & 1][mi] =
                        *reinterpret_cast<const bf16x8*>(aP[mi] + (tt + 1) * 32);
            }
            // B prefetch for tap+1 (same read-only slab buffer, no barrier)
            if (tap < 8)
                READBV(bvb[(tt + 1) & 1], cc, tap + 1);

            __builtin_amdgcn_s_setprio(1);
            #pragma unroll
            for (int mi = 0; mi < 4; ++mi)
                #pragma unroll
                for (int nj = 0; nj < 7; ++nj)
                    acc[mi][nj] = __builtin_amdgcn_mfma_f32_16x16x32_bf16(
                        aA[tt & 1][mi], bvb[tt & 1][nj], acc[mi][nj], 0, 0, 0);
            __builtin_amdgcn_s_setprio(0);
        }
        if (cc < 3) {
            WRITESLAB((cc + 1) & 1);             // compiler waits sreg's vmcnt
            if (cc < 2) LOADSLAB(cc + 2);
            asm volatile("s_waitcnt lgkmcnt(0)" ::: "memory");
            __builtin_amdgcn_s_barrier();
            READBV(bvb[(cc + 1) & 1], cc + 1, 0);   // refill: tt'=(cc+1)*9, (9x)&1=x&1
        }
    }

    // ---- epilogue: D col = lane&15, row = (lane>>4)*4 + reg ----
    const int pbase = r_blk * BNP + wc * 112;
    #pragma unroll
    for (int mi = 0; mi < 4; ++mi) {
        const f32x4 bv4 = *reinterpret_cast<const f32x4*>(
            &bias[m0 + wr * 64 + mi * 16 + lkh * 4]);
        #pragma unroll
        for (int nj = 0; nj < 7; ++nj) {
            const int p2 = pbase + nj * 16 + la;
            float* op = out + ((size_t)(n_img * K_OUT + m0 + wr * 64 + mi * 16 + lkh * 4))
                              * SPATIAL + p2;
            op[0]                   = acc[mi][nj][0] + bv4[0];
            op[SPATIAL]             = acc[mi][nj][1] + bv4[1];
            op[2 * SPATIAL]         = acc[mi][nj][2] + bv4[2];
            op[3 * (size_t)SPATIAL] = acc[mi][nj][3] + bv4[3];
        }
    }
#undef LOADSLAB
#undef WRITESLAB
#undef READBV
}

// ---------------- fallback (round-1 path) if ws is too small ----------------
#define LDK 40
__global__ __launch_bounds__(256)
void conv_mfma_fallback(const float* __restrict__ in,
                        const float* __restrict__ wraw,
                        const float* __restrict__ bias,
                        float* __restrict__ out) {
    __shared__ __attribute__((aligned(16))) unsigned short lA[BM * LDK];
    __shared__ __attribute__((aligned(16))) unsigned short lB[128 * LDK];
    const int tid = threadIdx.x;
    const int m0  = blockIdx.y * BM;
    const int g0  = blockIdx.x * 128;
    const int wave = tid >> 6, lane = tid & 63;
    const int wr = wave >> 1, wc = wave & 1;
    const int la = lane & 15, lkh = lane >> 4, lk = lkh * 8;

    f32x4 acc[4][4];
    #pragma unroll
    for (int i = 0; i < 4; ++i)
        #pragma unroll
        for (int j = 0; j < 4; ++j)
            acc[i][j] = (f32x4){0.f, 0.f, 0.f, 0.f};

    const int jj = tid & 127;
    const int kb = (tid >> 7) * 16;
    const int g = g0 + jj;
    const int nimg = g / SPATIAL;
    const int pos  = g % SPATIAL;
    const int oh = pos / HW, ow = pos % HW;

    for (int tap = 0; tap < 9; ++tap) {
        const int dr = tap / 3 - 1, dsx = tap % 3 - 1;
        const int ih = oh + dr, iw = ow + dsx;
        const bool valid = ((unsigned)ih < HW) && ((unsigned)iw < HW);
        const float* src = in + ((nimg * C_IN) * HW + ih) * HW + iw;
        for (int c0 = 0; c0 < C_IN; c0 += 32) {
            #pragma unroll
            for (int i = 0; i < 2; ++i) {
                const int ch = tid * 2 + i;
                const int row = ch >> 2;
                const int kp = (ch & 3) * 8;
                ushort8 v;
                #pragma unroll
                for (int e = 0; e < 8; ++e)
                    v[e] = f2bf(wraw[((m0 + row) * C_IN + c0 + kp + e) * 9 + tap]);
                *reinterpret_cast<ushort8*>(&lA[row * LDK + kp]) = v;
            }
            {
                ushort8 v0, v1;
                #pragma unroll
                for (int i = 0; i < 8; ++i)
                    v0[i] = f2bf(valid ? src[(c0 + kb + i) * SPATIAL] : 0.f);
                #pragma unroll
                for (int i = 0; i < 8; ++i)
                    v1[i] = f2bf(valid ? src[(c0 + kb + 8 + i) * SPATIAL] : 0.f);
                *reinterpret_cast<ushort8*>(&lB[jj * LDK + kb])     = v0;
                *reinterpret_cast<ushort8*>(&lB[jj * LDK + kb + 8]) = v1;
            }
            __syncthreads();
            bf16x8 af[4], bv[4];
            #pragma unroll
            for (int f = 0; f < 4; ++f) {
                af[f] = *reinterpret_cast<const bf16x8*>(&lA[(wr * 64 + f * 16 + la) * LDK + lk]);
                bv[f] = *reinterpret_cast<const bf16x8*>(&lB[(wc * 64 + f * 16 + la) * LDK + lk]);
            }
            #pragma unroll
            for (int fi = 0; fi < 4; ++fi)
                #pragma unroll
                for (int fj = 0; fj < 4; ++fj)
                    acc[fi][fj] = __builtin_amdgcn_mfma_f32_16x16x32_bf16(
                        af[fi], bv[fj], acc[fi][fj], 0, 0, 0);
            __syncthreads();
        }
    }
    const int mbase = m0 + wr * 64;
    const int cbase = g0 + wc * 64;
    #pragma unroll
    for (int fi = 0; fi < 4; ++fi) {
        float bvv[4];
        #pragma unroll
        for (int r = 0; r < 4; ++r)
            bvv[r] = bias[mbase + fi * 16 + lkh * 4 + r];
        #pragma unroll
        for (int fj = 0; fj < 4; ++fj) {
            const int gcol = cbase + fj * 16 + la;
            const int n2 = gcol / SPATIAL;
            const int p2 = gcol % SPATIAL;
            float* op = out + (size_t)(n2 * K_OUT) * SPATIAL + p2;
            #pragma unroll
            for (int r = 0; r < 4; ++r)
                op[(size_t)(mbase + fi * 16 + lkh * 4 + r) * SPATIAL] = acc[fi][fj][r] + bvv[r];
        }
    }
}

extern "C" void kernel_launch(void* const* d_in, const int* in_sizes, int n_in,
                              void* d_out, int out_size, void* d_ws, size_t ws_size,
                              hipStream_t stream) {
    const float* in   = (const float*)d_in[0];
    const float* w    = (const float*)d_in[1];
    const float* bias = (const float*)d_in[2];
    float* out = (float*)d_out;

    // ws layout (halves): pad [4*PADTOT_AL*32] | w2k [294912]
    const size_t pad_halves = 4ull * PADTOT_AL * 32ull;     // 13,779,968
    const size_t need_bytes = (pad_halves + 294912ull) * 2ull;  // ~28.15 MB

    if (ws_size >= need_bytes) {
        unsigned short* pad = (unsigned short*)d_ws;
        unsigned short* w2k = pad + pad_halves;
        border_zero<<<114, 256, 0, stream>>>(pad);
        wtrans_kernel<<<(K_OUT * GEMM_K) / 256, 256, 0, stream>>>(w, w2k);
        intrans_kernel<<<32 * HW, 256, 0, stream>>>(in, pad);
        conv_slab<<<(GEMM_N / BNP) * (K_OUT / BM), 256, 0, stream>>>(pad, w2k, bias, out);
    } else {
        dim3 grid(GEMM_N / 128, K_OUT / BM);
        conv_mfma_fallback<<<grid, 256, 0, stream>>>(in, w, bias, out);
    }
}

// Round 8
// 121.097 us; speedup vs baseline: 1.1944x; 1.0383x over previous
//
#include <hip/hip_runtime.h>
#include <hip/hip_bf16.h>
#include <stdint.h>

// DenseConv2d: input (32,128,56,56) f32, weight (256,128,3,3) f32, bias (256) f32
// stride 1, pad 1 -> out (32,256,56,56) f32.
// Round 8: m201-style phase discipline on the implicit GEMM.
// BM=BN=128, 4 waves (64x64 each), BK=32 (one (tap,cc) pair per step, 36 steps),
// 3 LDS buffers (48KB, chunked zero-conflict layout), 2-deep gload_lds prefetch
// with counted vmcnt(4), ONE barrier per K-step, lgkmcnt(0)+sched_barrier(0)
// before the MFMA cluster, setprio. 3 waves/SIMD, 3 blocks/CU.

typedef __attribute__((ext_vector_type(8))) short bf16x8;
typedef __attribute__((ext_vector_type(8))) unsigned short ushort8;
typedef __attribute__((ext_vector_type(4))) float f32x4;

#define HW       56
#define SPATIAL  3136
#define C_IN     128
#define K_OUT    256
#define GEMM_K   1152        // k = tap*128 + c
#define GEMM_N   100352      // 32*3136

#define PHW      58
#define PIMG     3364        // 58*58
#define PADTOT_AL 107656     // 32*3364 + 8 slack positions

#define BM       128
#define BN       128
#define BK       32
#define NSTEP    36          // 9 taps * 4 channel-chunks
#define BUF_H    8192        // halves per LDS buffer: A 4096 + B 4096 (16 KiB)

__device__ __forceinline__ unsigned short f2bf(float f) {
    union { float f; unsigned int u; } v; v.f = f;
    unsigned int u = v.u + 0x7FFFu + ((v.u >> 16) & 1u);   // RTNE
    return (unsigned short)(u >> 16);
}

__device__ __forceinline__ void gload16(const unsigned short* g, unsigned short* l) {
    __builtin_amdgcn_global_load_lds(
        (const __attribute__((address_space(1))) unsigned int*)(g),
        (__attribute__((address_space(3))) unsigned int*)(l),
        16, 0, 0);
}

// weight [256][128][3][3] f32 -> w2 [256][9tap][128c] bf16  (k = tap*128 + c)
__global__ void wtrans_kernel(const float* __restrict__ w, unsigned short* __restrict__ w2) {
    int idx = blockIdx.x * 256 + threadIdx.x;    // 294912
    int ko  = idx / GEMM_K;
    int r   = idx % GEMM_K;
    int tap = r >> 7;
    int c   = r & 127;
    w2[idx] = f2bf(w[(ko * C_IN + c) * 9 + tap]);
}

// zero only the border ring of pad[4][32][58*58][32] (1.9 MB, not 27.6 MB)
__global__ __launch_bounds__(256)
void border_zero(unsigned short* __restrict__ pad) {
    int idx = blockIdx.x * 256 + threadIdx.x;    // 4*32*228 = 29184
    if (idx >= 29184) return;
    int cc  = idx / 7296;
    int r   = idx % 7296;
    int img = r / 228;
    int p   = r % 228;
    int pos;
    if (p < 58)       pos = p;                       // top row
    else if (p < 116) pos = 57 * PHW + (p - 58);     // bottom row
    else { int i = p - 116; pos = (1 + (i >> 1)) * PHW + (i & 1) * 57; }
    unsigned short* d = pad + (size_t)cc * PADTOT_AL * 32
                      + ((size_t)img * PIMG + pos) * 32;
    const ushort8 z = (ushort8){0,0,0,0,0,0,0,0};
    *reinterpret_cast<ushort8*>(d)      = z;
    *reinterpret_cast<ushort8*>(d + 8)  = z;
    *reinterpret_cast<ushort8*>(d + 16) = z;
    *reinterpret_cast<ushort8*>(d + 24) = z;
}

// input [32][128][56][56] f32 -> pad[4cc][32img][58*58][32ch] bf16 (interior)
__global__ __launch_bounds__(256)
void intrans_kernel(const float* __restrict__ in, unsigned short* __restrict__ pad) {
    __shared__ __attribute__((aligned(16))) unsigned short l[56 * 136];
    const int bx = blockIdx.x;                   // 32*56
    const int n = bx / HW, h = bx % HW;
    const int tid = threadIdx.x;
    const float* src = in + (size_t)n * C_IN * SPATIAL + h * HW;
    #pragma unroll
    for (int i = 0; i < 28; ++i) {               // 7168 = 28*256
        int idx = i * 256 + tid;
        int c = idx / HW, w = idx % HW;
        l[w * 136 + c] = f2bf(src[(size_t)c * SPATIAL + w]);
    }
    __syncthreads();
    const int prow = n * PIMG + (h + 1) * PHW;
    #pragma unroll
    for (int j = 0; j < 4; ++j) {
        int chunk = j * 256 + tid;               // 896 = 56*16 chunks of 8 halves
        if (chunk < 896) {
            int w = chunk >> 4, c8 = chunk & 15;
            int cc = c8 >> 2, sub = c8 & 3;
            unsigned short* dst = pad + (size_t)cc * PADTOT_AL * 32
                                + (size_t)(prow + w + 1) * 32 + sub * 8;
            *reinterpret_cast<ushort8*>(dst) =
                *reinterpret_cast<const ushort8*>(&l[w * 136 + c8 * 8]);
        }
    }
}

// ---------------- main kernel: m201 phase template ----------------
// LDS chunk layout (round-4 verified, zero conflicts): each 16(rows/cols) x
// 32(k) bf16 subtile is one 1 KiB chunk; slot s holds (row s&15, kgran s>>4).
// gload_lds lane l fetches (row l&15, granule l>>4); compute lane l reads
// chunk_base + l*16B -> contiguous.
__global__ __launch_bounds__(256, 3)
void conv_phase(const unsigned short* __restrict__ pad,   // [4][PADTOT_AL][32]
                const unsigned short* __restrict__ w2,    // [256][9][128]
                const float* __restrict__ bias,
                float* __restrict__ out) {
    __shared__ __attribute__((aligned(16))) unsigned short lds[3 * BUF_H]; // 48 KiB

    const int tid  = threadIdx.x;
    const int wave = tid >> 6;
    const int lane = tid & 63;
    const int la   = lane & 15;
    const int lkh  = lane >> 4;
    const int gq   = lkh * 8;

    // bijective XCD swizzle: 1568 blocks = 8 * 196; nt-major pairs (2 m-tiles
    // of the same n-panel adjacent) for L2 B reuse; per-XCD B slice ~3.2 MB.
    const int bid = blockIdx.x;
    const int swz = (bid & 7) * 196 + (bid >> 3);
    const int mt  = swz & 1, nt = swz >> 1;       // nt 0..783
    const int m0  = mt * BM;
    const int g0  = nt * BN;

    const int wr = wave >> 1, wc = wave & 1;      // 2x2 waves, 64x64 tiles

    // ---- staging descriptors ----
    // wave stages A chunks {2w,2w+1} and B chunks {2w,2w+1}; lane l covers
    // (row/col l&15, k-granule l>>4) of its chunk.
    const unsigned short* asrc[2];
    #pragma unroll
    for (int i = 0; i < 2; ++i)
        asrc[i] = w2 + (size_t)(m0 + (wave * 2 + i) * 16 + la) * GEMM_K + gq;

    const unsigned short* bsrc[2];
    #pragma unroll
    for (int i = 0; i < 2; ++i) {
        int col = g0 + (wave * 2 + i) * 16 + la;
        int img = col / SPATIAL;
        int pos = col - img * SPATIAL;
        int oh  = pos / HW, ow = pos - oh * HW;
        int ppos = img * PIMG + (oh + 1) * PHW + (ow + 1);   // padded center
        bsrc[i] = pad + (size_t)ppos * 32 + gq;
    }

    f32x4 acc[4][4];
    #pragma unroll
    for (int i = 0; i < 4; ++i)
        #pragma unroll
        for (int j = 0; j < 4; ++j)
            acc[i][j] = (f32x4){0.f, 0.f, 0.f, 0.f};

    // stage step s (tap = s>>2, cc = s&3) into buffer bufi
    auto STAGE = [&](int s, int bufi) {
        const int tap = s >> 2, cc = s & 3;
        const int dr = tap / 3 - 1, dsx = tap % 3 - 1;
        unsigned short* dstA = &lds[bufi * BUF_H];
        unsigned short* dstB = dstA + 4096;
        const int aoff = tap * C_IN + cc * 32;
        const ptrdiff_t boff = (ptrdiff_t)cc * PADTOT_AL * 32 + (dr * PHW + dsx) * 32;
        gload16(asrc[0] + aoff, dstA + (wave * 2 + 0) * 512);
        gload16(asrc[1] + aoff, dstA + (wave * 2 + 1) * 512);
        gload16(bsrc[0] + boff, dstB + (wave * 2 + 0) * 512);
        gload16(bsrc[1] + boff, dstB + (wave * 2 + 1) * 512);
    };

    // prologue: 2 steps in flight
    STAGE(0, 0);
    STAGE(1, 1);
    asm volatile("s_waitcnt vmcnt(4)" ::: "memory");   // step-0 loads landed
    __builtin_amdgcn_s_barrier();

    #pragma unroll
    for (int t = 0; t < NSTEP; ++t) {
        const int cur = t % 3;
        const unsigned short* A = &lds[cur * BUF_H];
        const unsigned short* B = A + 4096;

        bf16x8 af[4], bv[4];
        #pragma unroll
        for (int mi = 0; mi < 4; ++mi)
            af[mi] = *reinterpret_cast<const bf16x8*>(&A[(wr * 4 + mi) * 512 + lane * 8]);
        #pragma unroll
        for (int nj = 0; nj < 4; ++nj)
            bv[nj] = *reinterpret_cast<const bf16x8*>(&B[(wc * 4 + nj) * 512 + lane * 8]);

        if (t + 2 < NSTEP)
            STAGE(t + 2, (t + 2) % 3);   // writes buf[(t+2)%3] != buf[cur], safe

        asm volatile("s_waitcnt lgkmcnt(0)" ::: "memory");
        __builtin_amdgcn_sched_barrier(0);            // rule #18: pin MFMAs after wait

        __builtin_amdgcn_s_setprio(1);
        #pragma unroll
        for (int mi = 0; mi < 4; ++mi)
            #pragma unroll
            for (int nj = 0; nj < 4; ++nj)
                acc[mi][nj] = __builtin_amdgcn_mfma_f32_16x16x32_bf16(
                    af[mi], bv[nj], acc[mi][nj], 0, 0, 0);
        __builtin_amdgcn_s_setprio(0);

        // end of step: my t+1 loads done (counted; t+2's stay in flight), barrier.
        if (t < NSTEP - 2) {
            asm volatile("s_waitcnt vmcnt(4)" ::: "memory");
            __builtin_amdgcn_s_barrier();
        } else if (t == NSTEP - 2) {
            asm volatile("s_waitcnt vmcnt(0)" ::: "memory");
            __builtin_amdgcn_s_barrier();
        }
    }

    // ---- epilogue: D col = lane&15, row = (lane>>4)*4 + reg ----
    const int mb = m0 + wr * 64;
    const int cb = g0 + wc * 64;
    #pragma unroll
    for (int mi = 0; mi < 4; ++mi) {
        const f32x4 bv4 = *reinterpret_cast<const f32x4*>(&bias[mb + mi * 16 + lkh * 4]);
        #pragma unroll
        for (int nj = 0; nj < 4; ++nj) {
            const int gcol = cb + nj * 16;           // 16-aligned: no image straddle
            const int n2 = gcol / SPATIAL;
            const int p2 = gcol - n2 * SPATIAL + la;
            float* op = out + ((size_t)(n2 * K_OUT + mb + mi * 16 + lkh * 4)) * SPATIAL + p2;
            op[0]                   = acc[mi][nj][0] + bv4[0];
            op[SPATIAL]             = acc[mi][nj][1] + bv4[1];
            op[2 * SPATIAL]         = acc[mi][nj][2] + bv4[2];
            op[3 * (size_t)SPATIAL] = acc[mi][nj][3] + bv4[3];
        }
    }
}

// ---------------- fallback (round-1 path) if ws is too small ----------------
#define LDK 40
__global__ __launch_bounds__(256)
void conv_mfma_fallback(const float* __restrict__ in,
                        const float* __restrict__ wraw,
                        const float* __restrict__ bias,
                        float* __restrict__ out) {
    __shared__ __attribute__((aligned(16))) unsigned short lA[BM * LDK];
    __shared__ __attribute__((aligned(16))) unsigned short lB[128 * LDK];
    const int tid = threadIdx.x;
    const int m0  = blockIdx.y * BM;
    const int g0  = blockIdx.x * 128;
    const int wave = tid >> 6, lane = tid & 63;
    const int wr = wave >> 1, wc = wave & 1;
    const int la = lane & 15, lkh = lane >> 4, lk = lkh * 8;

    f32x4 acc[4][4];
    #pragma unroll
    for (int i = 0; i < 4; ++i)
        #pragma unroll
        for (int j = 0; j < 4; ++j)
            acc[i][j] = (f32x4){0.f, 0.f, 0.f, 0.f};

    const int jj = tid & 127;
    const int kb = (tid >> 7) * 16;
    const int g = g0 + jj;
    const int nimg = g / SPATIAL;
    const int pos  = g % SPATIAL;
    const int oh = pos / HW, ow = pos % HW;

    for (int tap = 0; tap < 9; ++tap) {
        const int dr = tap / 3 - 1, dsx = tap % 3 - 1;
        const int ih = oh + dr, iw = ow + dsx;
        const bool valid = ((unsigned)ih < HW) && ((unsigned)iw < HW);
        const float* src = in + ((nimg * C_IN) * HW + ih) * HW + iw;
        for (int c0 = 0; c0 < C_IN; c0 += 32) {
            #pragma unroll
            for (int i = 0; i < 2; ++i) {
                const int ch = tid * 2 + i;
                const int row = ch >> 2;
                const int kp = (ch & 3) * 8;
                ushort8 v;
                #pragma unroll
                for (int e = 0; e < 8; ++e)
                    v[e] = f2bf(wraw[((m0 + row) * C_IN + c0 + kp + e) * 9 + tap]);
                *reinterpret_cast<ushort8*>(&lA[row * LDK + kp]) = v;
            }
            {
                ushort8 v0, v1;
                #pragma unroll
                for (int i = 0; i < 8; ++i)
                    v0[i] = f2bf(valid ? src[(c0 + kb + i) * SPATIAL] : 0.f);
                #pragma unroll
                for (int i = 0; i < 8; ++i)
                    v1[i] = f2bf(valid ? src[(c0 + kb + 8 + i) * SPATIAL] : 0.f);
                *reinterpret_cast<ushort8*>(&lB[jj * LDK + kb])     = v0;
                *reinterpret_cast<ushort8*>(&lB[jj * LDK + kb + 8]) = v1;
            }
            __syncthreads();
            bf16x8 af[4], bv[4];
            #pragma unroll
            for (int f = 0; f < 4; ++f) {
                af[f] = *reinterpret_cast<const bf16x8*>(&lA[(wr * 64 + f * 16 + la) * LDK + lk]);
                bv[f] = *reinterpret_cast<const bf16x8*>(&lB[(wc * 64 + f * 16 + la) * LDK + lk]);
            }
            #pragma unroll
            for (int fi = 0; fi < 4; ++fi)
                #pragma unroll
                for (int fj = 0; fj < 4; ++fj)
                    acc[fi][fj] = __builtin_amdgcn_mfma_f32_16x16x32_bf16(
                        af[fi], bv[fj], acc[fi][fj], 0, 0, 0);
            __syncthreads();
        }
    }
    const int mbase = m0 + wr * 64;
    const int cbase = g0 + wc * 64;
    #pragma unroll
    for (int fi = 0; fi < 4; ++fi) {
        float bvv[4];
        #pragma unroll
        for (int r = 0; r < 4; ++r)
            bvv[r] = bias[mbase + fi * 16 + lkh * 4 + r];
        #pragma unroll
        for (int fj = 0; fj < 4; ++fj) {
            const int gcol = cbase + fj * 16 + la;
            const int n2 = gcol / SPATIAL;
            const int p2 = gcol % SPATIAL;
            float* op = out + (size_t)(n2 * K_OUT) * SPATIAL + p2;
            #pragma unroll
            for (int r = 0; r < 4; ++r)
                op[(size_t)(mbase + fi * 16 + lkh * 4 + r) * SPATIAL] = acc[fi][fj][r] + bvv[r];
        }
    }
}

extern "C" void kernel_launch(void* const* d_in, const int* in_sizes, int n_in,
                              void* d_out, int out_size, void* d_ws, size_t ws_size,
                              hipStream_t stream) {
    const float* in   = (const float*)d_in[0];
    const float* w    = (const float*)d_in[1];
    const float* bias = (const float*)d_in[2];
    float* out = (float*)d_out;

    // ws layout (halves): pad [4*PADTOT_AL*32] | w2 [294912]
    const size_t pad_halves = 4ull * PADTOT_AL * 32ull;     // 13,779,968
    const size_t need_bytes = (pad_halves + 294912ull) * 2ull;  // ~28.15 MB

    if (ws_size >= need_bytes) {
        unsigned short* pad = (unsigned short*)d_ws;
        unsigned short* w2  = pad + pad_halves;
        border_zero<<<114, 256, 0, stream>>>(pad);
        wtrans_kernel<<<(K_OUT * GEMM_K) / 256, 256, 0, stream>>>(w, w2);
        intrans_kernel<<<32 * HW, 256, 0, stream>>>(in, pad);
        conv_phase<<<(GEMM_N / BN) * (K_OUT / BM), 256, 0, stream>>>(pad, w2, bias, out);
    } else {
        dim3 grid(GEMM_N / 128, K_OUT / BM);
        conv_mfma_fallback<<<grid, 256, 0, stream>>>(in, w, bias, out);
    }
}

// Round 9
// 113.728 us; speedup vs baseline: 1.2718x; 1.0648x over previous
//
#include <hip/hip_runtime.h>
#include <hip/hip_bf16.h>
#include <stdint.h>

// DenseConv2d: input (32,128,56,56) f32, weight (256,128,3,3) f32, bias (256) f32
// stride 1, pad 1 -> out (32,256,56,56) f32.
// Round 9: faithful m201 8-phase-style port. BM=256 x BN=128, 512 threads
// (8 waves, 4m x 2n, per-wave 64x64), K-tile=64 (tap-aligned), 2 phases/tile
// (16 MFMA each), double-buffered 2x48KB LDS (1 block/CU), per-phase
// [ds_read || gload_lds] -> bar -> lgkm0+schedbar -> setprio MFMA -> bar,
// vmcnt(0) once per tile. Chunked conflict-free LDS; contiguous A via w3.

typedef __attribute__((ext_vector_type(8))) short bf16x8;
typedef __attribute__((ext_vector_type(8))) unsigned short ushort8;
typedef __attribute__((ext_vector_type(4))) float f32x4;

#define HW       56
#define SPATIAL  3136
#define C_IN     128
#define K_OUT    256
#define GEMM_K   1152
#define GEMM_N   100352      // 32*3136

#define PHW      58
#define PIMG     3364        // 58*58
#define PADTOT_AL 107656     // 32*3364 + 8 slack positions

#define BM       256
#define BN       128
#define NTILE    18          // K-tiles of 64 (tap = t>>1, ch-half = (t&1)*64)
#define BUFH     24576       // halves per LDS buffer: A 16384 + B 8192 (48 KiB)

__device__ __forceinline__ unsigned short f2bf(float f) {
    union { float f; unsigned int u; } v; v.f = f;
    unsigned int u = v.u + 0x7FFFu + ((v.u >> 16) & 1u);   // RTNE
    return (unsigned short)(u >> 16);
}

__device__ __forceinline__ void gload16(const unsigned short* g, unsigned short* l) {
    __builtin_amdgcn_global_load_lds(
        (const __attribute__((address_space(1))) unsigned int*)(g),
        (__attribute__((address_space(3))) unsigned int*)(l),
        16, 0, 0);
}

// weight [256][128][3][3] f32 -> w3: chunk (rc,tap,cc) = 512 halves; slot l
// (l=0..63, 8 halves) holds W[row rc*16 + (l&15)][ch cc*32 + (l>>4)*8 + j][tap].
// A-staging gload then reads w3 + chunk*512 + lane*8: fully contiguous 1KB.
__global__ void wtrans_kernel(const float* __restrict__ w, unsigned short* __restrict__ w3) {
    int idx = blockIdx.x * 256 + threadIdx.x;    // 294912
    int rc   = idx / 18432;
    int rem  = idx % 18432;
    int tap  = rem / 2048;
    int rem2 = rem % 2048;
    int cc   = rem2 / 512;
    int s    = rem2 % 512;
    int l    = s >> 3, j = s & 7;
    int ko   = rc * 16 + (l & 15);
    int c    = cc * 32 + ((l >> 4) << 3) + j;
    w3[idx] = f2bf(w[(ko * C_IN + c) * 9 + tap]);
}

// zero only the border ring of pad[4][32][58*58][32] (1.9 MB)
__global__ __launch_bounds__(256)
void border_zero(unsigned short* __restrict__ pad) {
    int idx = blockIdx.x * 256 + threadIdx.x;    // 4*32*228 = 29184
    if (idx >= 29184) return;
    int cc  = idx / 7296;
    int r   = idx % 7296;
    int img = r / 228;
    int p   = r % 228;
    int pos;
    if (p < 58)       pos = p;
    else if (p < 116) pos = 57 * PHW + (p - 58);
    else { int i = p - 116; pos = (1 + (i >> 1)) * PHW + (i & 1) * 57; }
    unsigned short* d = pad + (size_t)cc * PADTOT_AL * 32
                      + ((size_t)img * PIMG + pos) * 32;
    const ushort8 z = (ushort8){0,0,0,0,0,0,0,0};
    *reinterpret_cast<ushort8*>(d)      = z;
    *reinterpret_cast<ushort8*>(d + 8)  = z;
    *reinterpret_cast<ushort8*>(d + 16) = z;
    *reinterpret_cast<ushort8*>(d + 24) = z;
}

// input [32][128][56][56] f32 -> pad[4cc][32img][58*58][32ch] bf16 (interior)
__global__ __launch_bounds__(256)
void intrans_kernel(const float* __restrict__ in, unsigned short* __restrict__ pad) {
    __shared__ __attribute__((aligned(16))) unsigned short l[56 * 136];
    const int bx = blockIdx.x;                   // 32*56
    const int n = bx / HW, h = bx % HW;
    const int tid = threadIdx.x;
    const float* src = in + (size_t)n * C_IN * SPATIAL + h * HW;
    #pragma unroll
    for (int i = 0; i < 28; ++i) {               // 7168 = 28*256
        int idx = i * 256 + tid;
        int c = idx / HW, w = idx % HW;
        l[w * 136 + c] = f2bf(src[(size_t)c * SPATIAL + w]);
    }
    __syncthreads();
    const int prow = n * PIMG + (h + 1) * PHW;
    #pragma unroll
    for (int j = 0; j < 4; ++j) {
        int chunk = j * 256 + tid;               // 896 = 56*16 chunks of 8 halves
        if (chunk < 896) {
            int w = chunk >> 4, c8 = chunk & 15;
            int cc = c8 >> 2, sub = c8 & 3;
            unsigned short* dst = pad + (size_t)cc * PADTOT_AL * 32
                                + (size_t)(prow + w + 1) * 32 + sub * 8;
            *reinterpret_cast<ushort8*>(dst) =
                *reinterpret_cast<const ushort8*>(&l[w * 136 + c8 * 8]);
        }
    }
}

// ---------------- main kernel ----------------
// LDS buffer layout (halves): A chunks [(rc*2+kc)*512] rc=0..15, then at 16384
// B chunks [(bc*2+kc)*512] bc=0..7. Chunk slot l = (row/col l&15, k-gran l>>4).
__global__ __launch_bounds__(512, 2)
void conv_m201(const unsigned short* __restrict__ pad,   // [4][PADTOT_AL][32]
               const unsigned short* __restrict__ w3,    // chunked weights
               const float* __restrict__ bias,
               float* __restrict__ out) {
    __shared__ __attribute__((aligned(16))) unsigned short lds[2 * BUFH]; // 96 KiB

    const int tid  = threadIdx.x;
    const int wave = tid >> 6;          // 0..7
    const int lane = tid & 63;
    const int la   = lane & 15;
    const int lkh  = lane >> 4;

    // bijective XCD swizzle: 784 blocks = 8 * 98
    const int bid = blockIdx.x;
    const int nt  = (bid & 7) * 98 + (bid >> 3);      // 0..783
    const int g0  = nt * BN;

    const int wr = wave >> 1, wc = wave & 1;          // 4m x 2n, 64x64 tiles

    // ---- staging descriptors ----
    // A: wave stages rchunks {2w, 2w+1}; source in w3 is contiguous per chunk.
    const unsigned short* aw0 = w3 + (size_t)(wave * 2 + 0) * 18432 + lane * 8;
    const unsigned short* aw1 = w3 + (size_t)(wave * 2 + 1) * 18432 + lane * 8;
    // B: wave stages col-chunk w (cols g0 + w*16 + la), per-lane padded addr.
    const unsigned short* bsrc;
    {
        int col = g0 + wave * 16 + la;
        int img = col / SPATIAL;
        int pos = col - img * SPATIAL;
        int oh  = pos / HW, ow = pos - oh * HW;
        bsrc = pad + (size_t)(img * PIMG + (oh + 1) * PHW + (ow + 1)) * 32 + lkh * 8;
    }

    f32x4 acc[4][4];
    #pragma unroll
    for (int i = 0; i < 4; ++i)
        #pragma unroll
        for (int j = 0; j < 4; ++j)
            acc[i][j] = (f32x4){0.f, 0.f, 0.f, 0.f};

    // stage phase kc of tile tn into buf[tn&1]: A rchunks 2w,2w+1 + B chunk w
    auto STAGE = [&](int tn, int kc) {
        const int tap = tn >> 1;
        const int cc  = (tn & 1) * 2 + kc;            // global 32-ch chunk 0..3
        const int dr = tap / 3 - 1, dsx = tap % 3 - 1;
        unsigned short* dst = &lds[(tn & 1) * BUFH];
        gload16(aw0 + (size_t)(tap * 4 + cc) * 512, dst + (wave * 4 + kc) * 512);
        gload16(aw1 + (size_t)(tap * 4 + cc) * 512, dst + (wave * 4 + 2 + kc) * 512);
        gload16(bsrc + (size_t)cc * PADTOT_AL * 32 + (dr * PHW + dsx) * 32,
                dst + 16384 + (wave * 2 + kc) * 512);
    };

    // prologue: tile 0 fully staged
    STAGE(0, 0); STAGE(0, 1);
    asm volatile("s_waitcnt vmcnt(0)" ::: "memory");
    __builtin_amdgcn_s_barrier();

    #pragma unroll
    for (int t = 0; t < NTILE; ++t) {
        const unsigned short* Ab = &lds[(t & 1) * BUFH];
        #pragma unroll
        for (int ks = 0; ks < 2; ++ks) {
            // phase: read this phase's frags, issue next tile's stage (3 loads)
            bf16x8 af[4], bv[4];
            #pragma unroll
            for (int mi = 0; mi < 4; ++mi)
                af[mi] = *reinterpret_cast<const bf16x8*>(
                    &Ab[((wr * 4 + mi) * 2 + ks) * 512 + lane * 8]);
            #pragma unroll
            for (int nj = 0; nj < 4; ++nj)
                bv[nj] = *reinterpret_cast<const bf16x8*>(
                    &Ab[16384 + ((wc * 4 + nj) * 2 + ks) * 512 + lane * 8]);

            if (t + 1 < NTILE) STAGE(t + 1, ks);

            __builtin_amdgcn_s_barrier();
            asm volatile("s_waitcnt lgkmcnt(0)" ::: "memory");
            __builtin_amdgcn_sched_barrier(0);

            __builtin_amdgcn_s_setprio(1);
            #pragma unroll
            for (int mi = 0; mi < 4; ++mi)
                #pragma unroll
                for (int nj = 0; nj < 4; ++nj)
                    acc[mi][nj] = __builtin_amdgcn_mfma_f32_16x16x32_bf16(
                        af[mi], bv[nj], acc[mi][nj], 0, 0, 0);
            __builtin_amdgcn_s_setprio(0);

            // once per tile: ensure next tile's 6 loads landed before its reads
            if (ks == 1 && t + 1 < NTILE)
                asm volatile("s_waitcnt vmcnt(0)" ::: "memory");
            __builtin_amdgcn_s_barrier();
        }
    }

    // ---- epilogue: D col = lane&15, row = (lane>>4)*4 + reg ----
    #pragma unroll
    for (int mi = 0; mi < 4; ++mi) {
        const int mb = wr * 64 + mi * 16 + lkh * 4;
        const f32x4 bv4 = *reinterpret_cast<const f32x4*>(&bias[mb]);
        #pragma unroll
        for (int nj = 0; nj < 4; ++nj) {
            const int gcol = g0 + wc * 64 + nj * 16;   // 16-aligned: one image
            const int n2 = gcol / SPATIAL;
            const int p2 = gcol - n2 * SPATIAL + la;
            float* op = out + ((size_t)(n2 * K_OUT + mb)) * SPATIAL + p2;
            op[0]                   = acc[mi][nj][0] + bv4[0];
            op[SPATIAL]             = acc[mi][nj][1] + bv4[1];
            op[2 * SPATIAL]         = acc[mi][nj][2] + bv4[2];
            op[3 * (size_t)SPATIAL] = acc[mi][nj][3] + bv4[3];
        }
    }
}

// ---------------- fallback (round-1 path) if ws is too small ----------------
#define LDK 40
__global__ __launch_bounds__(256)
void conv_mfma_fallback(const float* __restrict__ in,
                        const float* __restrict__ wraw,
                        const float* __restrict__ bias,
                        float* __restrict__ out) {
    __shared__ __attribute__((aligned(16))) unsigned short lA[128 * LDK];
    __shared__ __attribute__((aligned(16))) unsigned short lB[128 * LDK];
    const int tid = threadIdx.x;
    const int m0  = blockIdx.y * 128;
    const int g0  = blockIdx.x * 128;
    const int wave = tid >> 6, lane = tid & 63;
    const int wr = wave >> 1, wc = wave & 1;
    const int la = lane & 15, lkh = lane >> 4, lk = lkh * 8;

    f32x4 acc[4][4];
    #pragma unroll
    for (int i = 0; i < 4; ++i)
        #pragma unroll
        for (int j = 0; j < 4; ++j)
            acc[i][j] = (f32x4){0.f, 0.f, 0.f, 0.f};

    const int jj = tid & 127;
    const int kb = (tid >> 7) * 16;
    const int g = g0 + jj;
    const int nimg = g / SPATIAL;
    const int pos  = g % SPATIAL;
    const int oh = pos / HW, ow = pos % HW;

    for (int tap = 0; tap < 9; ++tap) {
        const int dr = tap / 3 - 1, dsx = tap % 3 - 1;
        const int ih = oh + dr, iw = ow + dsx;
        const bool valid = ((unsigned)ih < HW) && ((unsigned)iw < HW);
        const float* src = in + ((nimg * C_IN) * HW + ih) * HW + iw;
        for (int c0 = 0; c0 < C_IN; c0 += 32) {
            #pragma unroll
            for (int i = 0; i < 2; ++i) {
                const int ch = tid * 2 + i;
                const int row = ch >> 2;
                const int kp = (ch & 3) * 8;
                ushort8 v;
                #pragma unroll
                for (int e = 0; e < 8; ++e)
                    v[e] = f2bf(wraw[((m0 + row) * C_IN + c0 + kp + e) * 9 + tap]);
                *reinterpret_cast<ushort8*>(&lA[row * LDK + kp]) = v;
            }
            {
                ushort8 v0, v1;
                #pragma unroll
                for (int i = 0; i < 8; ++i)
                    v0[i] = f2bf(valid ? src[(c0 + kb + i) * SPATIAL] : 0.f);
                #pragma unroll
                for (int i = 0; i < 8; ++i)
                    v1[i] = f2bf(valid ? src[(c0 + kb + 8 + i) * SPATIAL] : 0.f);
                *reinterpret_cast<ushort8*>(&lB[jj * LDK + kb])     = v0;
                *reinterpret_cast<ushort8*>(&lB[jj * LDK + kb + 8]) = v1;
            }
            __syncthreads();
            bf16x8 af[4], bv[4];
            #pragma unroll
            for (int f = 0; f < 4; ++f) {
                af[f] = *reinterpret_cast<const bf16x8*>(&lA[(wr * 64 + f * 16 + la) * LDK + lk]);
                bv[f] = *reinterpret_cast<const bf16x8*>(&lB[(wc * 64 + f * 16 + la) * LDK + lk]);
            }
            #pragma unroll
            for (int fi = 0; fi < 4; ++fi)
                #pragma unroll
                for (int fj = 0; fj < 4; ++fj)
                    acc[fi][fj] = __builtin_amdgcn_mfma_f32_16x16x32_bf16(
                        af[fi], bv[fj], acc[fi][fj], 0, 0, 0);
            __syncthreads();
        }
    }
    const int mbase = m0 + wr * 64;
    const int cbase = g0 + wc * 64;
    #pragma unroll
    for (int fi = 0; fi < 4; ++fi) {
        float bvv[4];
        #pragma unroll
        for (int r = 0; r < 4; ++r)
            bvv[r] = bias[mbase + fi * 16 + lkh * 4 + r];
        #pragma unroll
        for (int fj = 0; fj < 4; ++fj) {
            const int gcol = cbase + fj * 16 + la;
            const int n2 = gcol / SPATIAL;
            const int p2 = gcol % SPATIAL;
            float* op = out + (size_t)(n2 * K_OUT) * SPATIAL + p2;
            #pragma unroll
            for (int r = 0; r < 4; ++r)
                op[(size_t)(mbase + fi * 16 + lkh * 4 + r) * SPATIAL] = acc[fi][fj][r] + bvv[r];
        }
    }
}

extern "C" void kernel_launch(void* const* d_in, const int* in_sizes, int n_in,
                              void* d_out, int out_size, void* d_ws, size_t ws_size,
                              hipStream_t stream) {
    const float* in   = (const float*)d_in[0];
    const float* w    = (const float*)d_in[1];
    const float* bias = (const float*)d_in[2];
    float* out = (float*)d_out;

    // ws layout (halves): pad [4*PADTOT_AL*32] | w3 [294912]
    const size_t pad_halves = 4ull * PADTOT_AL * 32ull;     // 13,779,968
    const size_t need_bytes = (pad_halves + 294912ull) * 2ull;  // ~28.15 MB

    if (ws_size >= need_bytes) {
        unsigned short* pad = (unsigned short*)d_ws;
        unsigned short* w3  = pad + pad_halves;
        border_zero<<<114, 256, 0, stream>>>(pad);
        wtrans_kernel<<<294912 / 256, 256, 0, stream>>>(w, w3);
        intrans_kernel<<<32 * HW, 256, 0, stream>>>(in, pad);
        conv_m201<<<GEMM_N / BN, 512, 0, stream>>>(pad, w3, bias, out);
    } else {
        dim3 grid(GEMM_N / 128, K_OUT / 128);
        conv_mfma_fallback<<<grid, 256, 0, stream>>>(in, w, bias, out);
    }
}

// Round 10
// 105.608 us; speedup vs baseline: 1.3696x; 1.0769x over previous
//
#include <hip/hip_runtime.h>
#include <hip/hip_bf16.h>
#include <stdint.h>

// DenseConv2d: input (32,128,56,56) f32, weight (256,128,3,3) f32, bias (256) f32
// stride 1, pad 1 -> out (32,256,56,56) f32.
// Round 10: round-9 m201 port + THE missing T4 piece: 3 LDS buffers, 2-tile
// prefetch depth, end-of-tile s_waitcnt vmcnt(6) -- the counter never drains
// to 0 inside the main loop (m218: counted-vs-drain0 = +38..73%).

typedef __attribute__((ext_vector_type(8))) short bf16x8;
typedef __attribute__((ext_vector_type(8))) unsigned short ushort8;
typedef __attribute__((ext_vector_type(4))) float f32x4;

#define HW       56
#define SPATIAL  3136
#define C_IN     128
#define K_OUT    256
#define GEMM_K   1152
#define GEMM_N   100352      // 32*3136

#define PHW      58
#define PIMG     3364        // 58*58
#define PADTOT_AL 107656     // 32*3364 + 8 slack positions

#define BM       256
#define BN       128
#define NTILE    18          // K-tiles of 64 (tap = t>>1, ch-half = t&1)
#define BUFH     24576       // halves per LDS buffer: A 16384 + B 8192 (48 KiB)

__device__ __forceinline__ unsigned short f2bf(float f) {
    union { float f; unsigned int u; } v; v.f = f;
    unsigned int u = v.u + 0x7FFFu + ((v.u >> 16) & 1u);   // RTNE
    return (unsigned short)(u >> 16);
}

__device__ __forceinline__ void gload16(const unsigned short* g, unsigned short* l) {
    __builtin_amdgcn_global_load_lds(
        (const __attribute__((address_space(1))) unsigned int*)(g),
        (__attribute__((address_space(3))) unsigned int*)(l),
        16, 0, 0);
}

// weight [256][128][3][3] f32 -> w3: chunk (rc,tap,cc) = 512 halves; slot l
// (l=0..63, 8 halves) holds W[row rc*16 + (l&15)][ch cc*32 + (l>>4)*8 + j][tap].
__global__ void wtrans_kernel(const float* __restrict__ w, unsigned short* __restrict__ w3) {
    int idx = blockIdx.x * 256 + threadIdx.x;    // 294912
    int rc   = idx / 18432;
    int rem  = idx % 18432;
    int tap  = rem / 2048;
    int rem2 = rem % 2048;
    int cc   = rem2 / 512;
    int s    = rem2 % 512;
    int l    = s >> 3, j = s & 7;
    int ko   = rc * 16 + (l & 15);
    int c    = cc * 32 + ((l >> 4) << 3) + j;
    w3[idx] = f2bf(w[(ko * C_IN + c) * 9 + tap]);
}

// zero only the border ring of pad[4][32][58*58][32] (1.9 MB)
__global__ __launch_bounds__(256)
void border_zero(unsigned short* __restrict__ pad) {
    int idx = blockIdx.x * 256 + threadIdx.x;    // 4*32*228 = 29184
    if (idx >= 29184) return;
    int cc  = idx / 7296;
    int r   = idx % 7296;
    int img = r / 228;
    int p   = r % 228;
    int pos;
    if (p < 58)       pos = p;
    else if (p < 116) pos = 57 * PHW + (p - 58);
    else { int i = p - 116; pos = (1 + (i >> 1)) * PHW + (i & 1) * 57; }
    unsigned short* d = pad + (size_t)cc * PADTOT_AL * 32
                      + ((size_t)img * PIMG + pos) * 32;
    const ushort8 z = (ushort8){0,0,0,0,0,0,0,0};
    *reinterpret_cast<ushort8*>(d)      = z;
    *reinterpret_cast<ushort8*>(d + 8)  = z;
    *reinterpret_cast<ushort8*>(d + 16) = z;
    *reinterpret_cast<ushort8*>(d + 24) = z;
}

// input [32][128][56][56] f32 -> pad[4cc][32img][58*58][32ch] bf16 (interior)
__global__ __launch_bounds__(256)
void intrans_kernel(const float* __restrict__ in, unsigned short* __restrict__ pad) {
    __shared__ __attribute__((aligned(16))) unsigned short l[56 * 136];
    const int bx = blockIdx.x;                   // 32*56
    const int n = bx / HW, h = bx % HW;
    const int tid = threadIdx.x;
    const float* src = in + (size_t)n * C_IN * SPATIAL + h * HW;
    #pragma unroll
    for (int i = 0; i < 28; ++i) {               // 7168 = 28*256
        int idx = i * 256 + tid;
        int c = idx / HW, w = idx % HW;
        l[w * 136 + c] = f2bf(src[(size_t)c * SPATIAL + w]);
    }
    __syncthreads();
    const int prow = n * PIMG + (h + 1) * PHW;
    #pragma unroll
    for (int j = 0; j < 4; ++j) {
        int chunk = j * 256 + tid;               // 896 = 56*16 chunks of 8 halves
        if (chunk < 896) {
            int w = chunk >> 4, c8 = chunk & 15;
            int cc = c8 >> 2, sub = c8 & 3;
            unsigned short* dst = pad + (size_t)cc * PADTOT_AL * 32
                                + (size_t)(prow + w + 1) * 32 + sub * 8;
            *reinterpret_cast<ushort8*>(dst) =
                *reinterpret_cast<const ushort8*>(&l[w * 136 + c8 * 8]);
        }
    }
}

// ---------------- main kernel ----------------
// LDS buffer layout (halves): A chunks [(rc*2+kc)*512] rc=0..15, then at 16384
// B chunks [(bc*2+kc)*512] bc=0..7. Chunk slot l = (row/col l&15, k-gran l>>4).
__global__ __launch_bounds__(512, 1)
void conv_m201(const unsigned short* __restrict__ pad,   // [4][PADTOT_AL][32]
               const unsigned short* __restrict__ w3,    // chunked weights
               const float* __restrict__ bias,
               float* __restrict__ out) {
    __shared__ __attribute__((aligned(16))) unsigned short lds[3 * BUFH]; // 144 KiB

    const int tid  = threadIdx.x;
    const int wave = tid >> 6;          // 0..7
    const int lane = tid & 63;
    const int la   = lane & 15;
    const int lkh  = lane >> 4;

    // bijective XCD swizzle: 784 blocks = 8 * 98
    const int bid = blockIdx.x;
    const int nt  = (bid & 7) * 98 + (bid >> 3);      // 0..783
    const int g0  = nt * BN;

    const int wr = wave >> 1, wc = wave & 1;          // 4m x 2n, 64x64 tiles

    // ---- staging descriptors ----
    const unsigned short* aw0 = w3 + (size_t)(wave * 2 + 0) * 18432 + lane * 8;
    const unsigned short* aw1 = w3 + (size_t)(wave * 2 + 1) * 18432 + lane * 8;
    const unsigned short* bsrc;
    {
        int col = g0 + wave * 16 + la;
        int img = col / SPATIAL;
        int pos = col - img * SPATIAL;
        int oh  = pos / HW, ow = pos - oh * HW;
        bsrc = pad + (size_t)(img * PIMG + (oh + 1) * PHW + (ow + 1)) * 32 + lkh * 8;
    }

    f32x4 acc[4][4];
    #pragma unroll
    for (int i = 0; i < 4; ++i)
        #pragma unroll
        for (int j = 0; j < 4; ++j)
            acc[i][j] = (f32x4){0.f, 0.f, 0.f, 0.f};

    // stage phase kc of tile tn into buf[tn%3]: A rchunks 2w,2w+1 + B chunk w
    auto STAGE = [&](int tn, int kc) {
        const int tap = tn >> 1;
        const int cc  = (tn & 1) * 2 + kc;            // global 32-ch chunk 0..3
        const int dr = tap / 3 - 1, dsx = tap % 3 - 1;
        unsigned short* dst = &lds[(tn % 3) * BUFH];
        gload16(aw0 + (size_t)(tap * 4 + cc) * 512, dst + (wave * 4 + kc) * 512);
        gload16(aw1 + (size_t)(tap * 4 + cc) * 512, dst + (wave * 4 + 2 + kc) * 512);
        gload16(bsrc + (size_t)cc * PADTOT_AL * 32 + (dr * PHW + dsx) * 32,
                dst + 16384 + (wave * 2 + kc) * 512);
    };

    // prologue: tiles 0 and 1 staged (12 loads/wave); wait tile-0 (6 remain)
    STAGE(0, 0); STAGE(0, 1);
    STAGE(1, 0); STAGE(1, 1);
    asm volatile("s_waitcnt vmcnt(6)" ::: "memory");
    __builtin_amdgcn_s_barrier();

    #pragma unroll
    for (int t = 0; t < NTILE; ++t) {
        const unsigned short* Ab = &lds[(t % 3) * BUFH];
        #pragma unroll
        for (int ks = 0; ks < 2; ++ks) {
            bf16x8 af[4], bv[4];
            #pragma unroll
            for (int mi = 0; mi < 4; ++mi)
                af[mi] = *reinterpret_cast<const bf16x8*>(
                    &Ab[((wr * 4 + mi) * 2 + ks) * 512 + lane * 8]);
            #pragma unroll
            for (int nj = 0; nj < 4; ++nj)
                bv[nj] = *reinterpret_cast<const bf16x8*>(
                    &Ab[16384 + ((wc * 4 + nj) * 2 + ks) * 512 + lane * 8]);

            if (t + 2 < NTILE) STAGE(t + 2, ks);   // buf (t+2)%3: not cur, not t+1

            __builtin_amdgcn_s_barrier();
            asm volatile("s_waitcnt lgkmcnt(0)" ::: "memory");
            __builtin_amdgcn_sched_barrier(0);

            __builtin_amdgcn_s_setprio(1);
            #pragma unroll
            for (int mi = 0; mi < 4; ++mi)
                #pragma unroll
                for (int nj = 0; nj < 4; ++nj)
                    acc[mi][nj] = __builtin_amdgcn_mfma_f32_16x16x32_bf16(
                        af[mi], bv[nj], acc[mi][nj], 0, 0, 0);
            __builtin_amdgcn_s_setprio(0);

            // end of tile: tile t+1's 6 loads landed; tile t+2's 6 stay in
            // flight (counted wait — NEVER 0 in the loop; T4/m218).
            if (ks == 1 && t + 1 < NTILE)
                asm volatile("s_waitcnt vmcnt(6)" ::: "memory");
            __builtin_amdgcn_s_barrier();
        }
    }

    // ---- epilogue: D col = lane&15, row = (lane>>4)*4 + reg ----
    #pragma unroll
    for (int mi = 0; mi < 4; ++mi) {
        const int mb = wr * 64 + mi * 16 + lkh * 4;
        const f32x4 bv4 = *reinterpret_cast<const f32x4*>(&bias[mb]);
        #pragma unroll
        for (int nj = 0; nj < 4; ++nj) {
            const int gcol = g0 + wc * 64 + nj * 16;   // 16-aligned: one image
            const int n2 = gcol / SPATIAL;
            const int p2 = gcol - n2 * SPATIAL + la;
            float* op = out + ((size_t)(n2 * K_OUT + mb)) * SPATIAL + p2;
            op[0]                   = acc[mi][nj][0] + bv4[0];
            op[SPATIAL]             = acc[mi][nj][1] + bv4[1];
            op[2 * SPATIAL]         = acc[mi][nj][2] + bv4[2];
            op[3 * (size_t)SPATIAL] = acc[mi][nj][3] + bv4[3];
        }
    }
}

// ---------------- fallback (round-1 path) if ws is too small ----------------
#define LDK 40
__global__ __launch_bounds__(256)
void conv_mfma_fallback(const float* __restrict__ in,
                        const float* __restrict__ wraw,
                        const float* __restrict__ bias,
                        float* __restrict__ out) {
    __shared__ __attribute__((aligned(16))) unsigned short lA[128 * LDK];
    __shared__ __attribute__((aligned(16))) unsigned short lB[128 * LDK];
    const int tid = threadIdx.x;
    const int m0  = blockIdx.y * 128;
    const int g0  = blockIdx.x * 128;
    const int wave = tid >> 6, lane = tid & 63;
    const int wr = wave >> 1, wc = wave & 1;
    const int la = lane & 15, lkh = lane >> 4, lk = lkh * 8;

    f32x4 acc[4][4];
    #pragma unroll
    for (int i = 0; i < 4; ++i)
        #pragma unroll
        for (int j = 0; j < 4; ++j)
            acc[i][j] = (f32x4){0.f, 0.f, 0.f, 0.f};

    const int jj = tid & 127;
    const int kb = (tid >> 7) * 16;
    const int g = g0 + jj;
    const int nimg = g / SPATIAL;
    const int pos  = g % SPATIAL;
    const int oh = pos / HW, ow = pos % HW;

    for (int tap = 0; tap < 9; ++tap) {
        const int dr = tap / 3 - 1, dsx = tap % 3 - 1;
        const int ih = oh + dr, iw = ow + dsx;
        const bool valid = ((unsigned)ih < HW) && ((unsigned)iw < HW);
        const float* src = in + ((nimg * C_IN) * HW + ih) * HW + iw;
        for (int c0 = 0; c0 < C_IN; c0 += 32) {
            #pragma unroll
            for (int i = 0; i < 2; ++i) {
                const int ch = tid * 2 + i;
                const int row = ch >> 2;
                const int kp = (ch & 3) * 8;
                ushort8 v;
                #pragma unroll
                for (int e = 0; e < 8; ++e)
                    v[e] = f2bf(wraw[((m0 + row) * C_IN + c0 + kp + e) * 9 + tap]);
                *reinterpret_cast<ushort8*>(&lA[row * LDK + kp]) = v;
            }
            {
                ushort8 v0, v1;
                #pragma unroll
                for (int i = 0; i < 8; ++i)
                    v0[i] = f2bf(valid ? src[(c0 + kb + i) * SPATIAL] : 0.f);
                #pragma unroll
                for (int i = 0; i < 8; ++i)
                    v1[i] = f2bf(valid ? src[(c0 + kb + 8 + i) * SPATIAL] : 0.f);
                *reinterpret_cast<ushort8*>(&lB[jj * LDK + kb])     = v0;
                *reinterpret_cast<ushort8*>(&lB[jj * LDK + kb + 8]) = v1;
            }
            __syncthreads();
            bf16x8 af[4], bv[4];
            #pragma unroll
            for (int f = 0; f < 4; ++f) {
                af[f] = *reinterpret_cast<const bf16x8*>(&lA[(wr * 64 + f * 16 + la) * LDK + lk]);
                bv[f] = *reinterpret_cast<const bf16x8*>(&lB[(wc * 64 + f * 16 + la) * LDK + lk]);
            }
            #pragma unroll
            for (int fi = 0; fi < 4; ++fi)
                #pragma unroll
                for (int fj = 0; fj < 4; ++fj)
                    acc[fi][fj] = __builtin_amdgcn_mfma_f32_16x16x32_bf16(
                        af[fi], bv[fj], acc[fi][fj], 0, 0, 0);
            __syncthreads();
        }
    }
    const int mbase = m0 + wr * 64;
    const int cbase = g0 + wc * 64;
    #pragma unroll
    for (int fi = 0; fi < 4; ++fi) {
        float bvv[4];
        #pragma unroll
        for (int r = 0; r < 4; ++r)
            bvv[r] = bias[mbase + fi * 16 + lkh * 4 + r];
        #pragma unroll
        for (int fj = 0; fj < 4; ++fj) {
            const int gcol = cbase + fj * 16 + la;
            const int n2 = gcol / SPATIAL;
            const int p2 = gcol % SPATIAL;
            float* op = out + (size_t)(n2 * K_OUT) * SPATIAL + p2;
            #pragma unroll
            for (int r = 0; r < 4; ++r)
                op[(size_t)(mbase + fi * 16 + lkh * 4 + r) * SPATIAL] = acc[fi][fj][r] + bvv[r];
        }
    }
}

extern "C" void kernel_launch(void* const* d_in, const int* in_sizes, int n_in,
                              void* d_out, int out_size, void* d_ws, size_t ws_size,
                              hipStream_t stream) {
    const float* in   = (const float*)d_in[0];
    const float* w    = (const float*)d_in[1];
    const float* bias = (const float*)d_in[2];
    float* out = (float*)d_out;

    // ws layout (halves): pad [4*PADTOT_AL*32] | w3 [294912]
    const size_t pad_halves = 4ull * PADTOT_AL * 32ull;     // 13,779,968
    const size_t need_bytes = (pad_halves + 294912ull) * 2ull;  // ~28.15 MB

    if (ws_size >= need_bytes) {
        unsigned short* pad = (unsigned short*)d_ws;
        unsigned short* w3  = pad + pad_halves;
        border_zero<<<114, 256, 0, stream>>>(pad);
        wtrans_kernel<<<294912 / 256, 256, 0, stream>>>(w, w3);
        intrans_kernel<<<32 * HW, 256, 0, stream>>>(in, pad);
        conv_m201<<<GEMM_N / BN, 512, 0, stream>>>(pad, w3, bias, out);
    } else {
        dim3 grid(GEMM_N / 128, K_OUT / 128);
        conv_mfma_fallback<<<grid, 256, 0, stream>>>(in, w, bias, out);
    }
}

// Round 11
// 100.354 us; speedup vs baseline: 1.4413x; 1.0524x over previous
//
#include <hip/hip_runtime.h>
#include <hip/hip_bf16.h>
#include <stdint.h>

// DenseConv2d: input (32,128,56,56) f32, weight (256,128,3,3) f32, bias (256) f32
// stride 1, pad 1 -> out (32,256,56,56) f32.
// Round 11: round-10 data path + ONE barrier per K-tile and cross-phase
// register-fragment pipelining: each 16-MFMA cluster overlaps the NEXT
// phase's 8 ds_reads (counted lgkmcnt(8), no cold drains before MFMA-A).
// Barriers 72 -> 18. Formally race-checked (reads drain via lgkmcnt(0)
// before the barrier preceding any buffer rewrite; cross-wave buf[t+1]
// reads only after vmcnt(6)+barrier).

typedef __attribute__((ext_vector_type(8))) short bf16x8;
typedef __attribute__((ext_vector_type(8))) unsigned short ushort8;
typedef __attribute__((ext_vector_type(4))) float f32x4;

#define HW       56
#define SPATIAL  3136
#define C_IN     128
#define K_OUT    256
#define GEMM_K   1152
#define GEMM_N   100352      // 32*3136

#define PHW      58
#define PIMG     3364        // 58*58
#define PADTOT_AL 107656     // 32*3364 + 8 slack positions

#define BM       256
#define BN       128
#define NTILE    18          // K-tiles of 64 (tap = t>>1, ch-half = t&1)
#define BUFH     24576       // halves per LDS buffer: A 16384 + B 8192 (48 KiB)

__device__ __forceinline__ unsigned short f2bf(float f) {
    union { float f; unsigned int u; } v; v.f = f;
    unsigned int u = v.u + 0x7FFFu + ((v.u >> 16) & 1u);   // RTNE
    return (unsigned short)(u >> 16);
}

__device__ __forceinline__ void gload16(const unsigned short* g, unsigned short* l) {
    __builtin_amdgcn_global_load_lds(
        (const __attribute__((address_space(1))) unsigned int*)(g),
        (__attribute__((address_space(3))) unsigned int*)(l),
        16, 0, 0);
}

// weight [256][128][3][3] f32 -> w3: chunk (rc,tap,cc) = 512 halves; slot l
// (l=0..63, 8 halves) holds W[row rc*16 + (l&15)][ch cc*32 + (l>>4)*8 + j][tap].
__global__ void wtrans_kernel(const float* __restrict__ w, unsigned short* __restrict__ w3) {
    int idx = blockIdx.x * 256 + threadIdx.x;    // 294912
    int rc   = idx / 18432;
    int rem  = idx % 18432;
    int tap  = rem / 2048;
    int rem2 = rem % 2048;
    int cc   = rem2 / 512;
    int s    = rem2 % 512;
    int l    = s >> 3, j = s & 7;
    int ko   = rc * 16 + (l & 15);
    int c    = cc * 32 + ((l >> 4) << 3) + j;
    w3[idx] = f2bf(w[(ko * C_IN + c) * 9 + tap]);
}

// zero only the border ring of pad[4][32][58*58][32] (1.9 MB)
__global__ __launch_bounds__(256)
void border_zero(unsigned short* __restrict__ pad) {
    int idx = blockIdx.x * 256 + threadIdx.x;    // 4*32*228 = 29184
    if (idx >= 29184) return;
    int cc  = idx / 7296;
    int r   = idx % 7296;
    int img = r / 228;
    int p   = r % 228;
    int pos;
    if (p < 58)       pos = p;
    else if (p < 116) pos = 57 * PHW + (p - 58);
    else { int i = p - 116; pos = (1 + (i >> 1)) * PHW + (i & 1) * 57; }
    unsigned short* d = pad + (size_t)cc * PADTOT_AL * 32
                      + ((size_t)img * PIMG + pos) * 32;
    const ushort8 z = (ushort8){0,0,0,0,0,0,0,0};
    *reinterpret_cast<ushort8*>(d)      = z;
    *reinterpret_cast<ushort8*>(d + 8)  = z;
    *reinterpret_cast<ushort8*>(d + 16) = z;
    *reinterpret_cast<ushort8*>(d + 24) = z;
}

// input [32][128][56][56] f32 -> pad[4cc][32img][58*58][32ch] bf16 (interior)
__global__ __launch_bounds__(256)
void intrans_kernel(const float* __restrict__ in, unsigned short* __restrict__ pad) {
    __shared__ __attribute__((aligned(16))) unsigned short l[56 * 136];
    const int bx = blockIdx.x;                   // 32*56
    const int n = bx / HW, h = bx % HW;
    const int tid = threadIdx.x;
    const float* src = in + (size_t)n * C_IN * SPATIAL + h * HW;
    #pragma unroll
    for (int i = 0; i < 28; ++i) {               // 7168 = 28*256
        int idx = i * 256 + tid;
        int c = idx / HW, w = idx % HW;
        l[w * 136 + c] = f2bf(src[(size_t)c * SPATIAL + w]);
    }
    __syncthreads();
    const int prow = n * PIMG + (h + 1) * PHW;
    #pragma unroll
    for (int j = 0; j < 4; ++j) {
        int chunk = j * 256 + tid;               // 896 = 56*16 chunks of 8 halves
        if (chunk < 896) {
            int w = chunk >> 4, c8 = chunk & 15;
            int cc = c8 >> 2, sub = c8 & 3;
            unsigned short* dst = pad + (size_t)cc * PADTOT_AL * 32
                                + (size_t)(prow + w + 1) * 32 + sub * 8;
            *reinterpret_cast<ushort8*>(dst) =
                *reinterpret_cast<const ushort8*>(&l[w * 136 + c8 * 8]);
        }
    }
}

// ---------------- main kernel ----------------
// LDS buffer layout (halves): A chunks [(rc*2+kc)*512] rc=0..15, then at 16384
// B chunks [(bc*2+kc)*512] bc=0..7. Chunk slot l = (row/col l&15, k-gran l>>4).
__global__ __launch_bounds__(512, 1)
void conv_pipe(const unsigned short* __restrict__ pad,   // [4][PADTOT_AL][32]
               const unsigned short* __restrict__ w3,    // chunked weights
               const float* __restrict__ bias,
               float* __restrict__ out) {
    __shared__ __attribute__((aligned(16))) unsigned short lds[3 * BUFH]; // 144 KiB

    const int tid  = threadIdx.x;
    const int wave = tid >> 6;          // 0..7
    const int lane = tid & 63;
    const int la   = lane & 15;
    const int lkh  = lane >> 4;

    // bijective XCD swizzle: 784 blocks = 8 * 98
    const int bid = blockIdx.x;
    const int nt  = (bid & 7) * 98 + (bid >> 3);      // 0..783
    const int g0  = nt * BN;

    const int wr = wave >> 1, wc = wave & 1;          // 4m x 2n, 64x64 tiles

    // ---- staging descriptors ----
    const unsigned short* aw0 = w3 + (size_t)(wave * 2 + 0) * 18432 + lane * 8;
    const unsigned short* aw1 = w3 + (size_t)(wave * 2 + 1) * 18432 + lane * 8;
    const unsigned short* bsrc;
    {
        int col = g0 + wave * 16 + la;
        int img = col / SPATIAL;
        int pos = col - img * SPATIAL;
        int oh  = pos / HW, ow = pos - oh * HW;
        bsrc = pad + (size_t)(img * PIMG + (oh + 1) * PHW + (ow + 1)) * 32 + lkh * 8;
    }

    f32x4 acc[4][4];
    #pragma unroll
    for (int i = 0; i < 4; ++i)
        #pragma unroll
        for (int j = 0; j < 4; ++j)
            acc[i][j] = (f32x4){0.f, 0.f, 0.f, 0.f};

    // stage phase kc of tile tn into buf[tn%3]
    auto STAGE = [&](int tn, int kc) {
        const int tap = tn >> 1;
        const int cc  = (tn & 1) * 2 + kc;            // global 32-ch chunk 0..3
        const int dr = tap / 3 - 1, dsx = tap % 3 - 1;
        unsigned short* dst = &lds[(tn % 3) * BUFH];
        gload16(aw0 + (size_t)(tap * 4 + cc) * 512, dst + (wave * 4 + kc) * 512);
        gload16(aw1 + (size_t)(tap * 4 + cc) * 512, dst + (wave * 4 + 2 + kc) * 512);
        gload16(bsrc + (size_t)cc * PADTOT_AL * 32 + (dr * PHW + dsx) * 32,
                dst + 16384 + (wave * 2 + kc) * 512);
    };

    // register fragment double-buffer (named, statically indexed — rule #20)
    bf16x8 a0[4], b0[4], a1[4], b1[4];

    auto READ0 = [&](int tn, int ks) {
        const unsigned short* Ab = &lds[(tn % 3) * BUFH];
        #pragma unroll
        for (int mi = 0; mi < 4; ++mi)
            a0[mi] = *reinterpret_cast<const bf16x8*>(
                &Ab[((wr * 4 + mi) * 2 + ks) * 512 + lane * 8]);
        #pragma unroll
        for (int nj = 0; nj < 4; ++nj)
            b0[nj] = *reinterpret_cast<const bf16x8*>(
                &Ab[16384 + ((wc * 4 + nj) * 2 + ks) * 512 + lane * 8]);
    };
    auto READ1 = [&](int tn, int ks) {
        const unsigned short* Ab = &lds[(tn % 3) * BUFH];
        #pragma unroll
        for (int mi = 0; mi < 4; ++mi)
            a1[mi] = *reinterpret_cast<const bf16x8*>(
                &Ab[((wr * 4 + mi) * 2 + ks) * 512 + lane * 8]);
        #pragma unroll
        for (int nj = 0; nj < 4; ++nj)
            b1[nj] = *reinterpret_cast<const bf16x8*>(
                &Ab[16384 + ((wc * 4 + nj) * 2 + ks) * 512 + lane * 8]);
    };

    // prologue: tiles 0 and 1 staged; wait tile-0 (tile-1's 6 stay in flight)
    STAGE(0, 0); STAGE(0, 1);
    STAGE(1, 0); STAGE(1, 1);
    asm volatile("s_waitcnt vmcnt(6)" ::: "memory");
    __builtin_amdgcn_s_barrier();
    asm volatile("" ::: "memory");
    READ0(0, 0);                       // 8 ds_read, in flight into the loop

    #pragma unroll
    for (int t = 0; t < NTILE; ++t) {
        // phase A: issue next-phase reads + stage, then MFMA on G0
        READ1(t, 1);                   // 8 ds_read (buf[t%3])
        if (t + 2 < NTILE) STAGE(t + 2, 0);
        asm volatile("s_waitcnt lgkmcnt(8)" ::: "memory");   // G0 done, G1 flying
        __builtin_amdgcn_sched_barrier(0);
        __builtin_amdgcn_s_setprio(1);
        #pragma unroll
        for (int mi = 0; mi < 4; ++mi)
            #pragma unroll
            for (int nj = 0; nj < 4; ++nj)
                acc[mi][nj] = __builtin_amdgcn_mfma_f32_16x16x32_bf16(
                    a0[mi], b0[nj], acc[mi][nj], 0, 0, 0);
        __builtin_amdgcn_s_setprio(0);

        // phase B: finish staging, drain reads, ONE barrier, prefetch-read
        // next tile's first phase, then MFMA on G1
        if (t + 2 < NTILE) STAGE(t + 2, 1);
        asm volatile("s_waitcnt lgkmcnt(0)" ::: "memory");   // all reads of buf[t%3] drained
        __builtin_amdgcn_sched_barrier(0);
        if (t + 1 < NTILE) {
            if (t + 2 < NTILE)
                asm volatile("s_waitcnt vmcnt(6)" ::: "memory");  // t+1 landed; t+2 flying
            else
                asm volatile("s_waitcnt vmcnt(0)" ::: "memory");
            __builtin_amdgcn_s_barrier();
            asm volatile("" ::: "memory");
            READ0(t + 1, 0);           // 8 ds_read (buf[(t+1)%3]), fly over MFMA-B
        }
        __builtin_amdgcn_s_setprio(1);
        #pragma unroll
        for (int mi = 0; mi < 4; ++mi)
            #pragma unroll
            for (int nj = 0; nj < 4; ++nj)
                acc[mi][nj] = __builtin_amdgcn_mfma_f32_16x16x32_bf16(
                    a1[mi], b1[nj], acc[mi][nj], 0, 0, 0);
        __builtin_amdgcn_s_setprio(0);
    }

    // ---- epilogue: D col = lane&15, row = (lane>>4)*4 + reg ----
    #pragma unroll
    for (int mi = 0; mi < 4; ++mi) {
        const int mb = wr * 64 + mi * 16 + lkh * 4;
        const f32x4 bv4 = *reinterpret_cast<const f32x4*>(&bias[mb]);
        #pragma unroll
        for (int nj = 0; nj < 4; ++nj) {
            const int gcol = g0 + wc * 64 + nj * 16;   // 16-aligned: one image
            const int n2 = gcol / SPATIAL;
            const int p2 = gcol - n2 * SPATIAL + la;
            float* op = out + ((size_t)(n2 * K_OUT + mb)) * SPATIAL + p2;
            op[0]                   = acc[mi][nj][0] + bv4[0];
            op[SPATIAL]             = acc[mi][nj][1] + bv4[1];
            op[2 * SPATIAL]         = acc[mi][nj][2] + bv4[2];
            op[3 * (size_t)SPATIAL] = acc[mi][nj][3] + bv4[3];
        }
    }
}

// ---------------- fallback (round-1 path) if ws is too small ----------------
#define LDK 40
__global__ __launch_bounds__(256)
void conv_mfma_fallback(const float* __restrict__ in,
                        const float* __restrict__ wraw,
                        const float* __restrict__ bias,
                        float* __restrict__ out) {
    __shared__ __attribute__((aligned(16))) unsigned short lA[128 * LDK];
    __shared__ __attribute__((aligned(16))) unsigned short lB[128 * LDK];
    const int tid = threadIdx.x;
    const int m0  = blockIdx.y * 128;
    const int g0  = blockIdx.x * 128;
    const int wave = tid >> 6, lane = tid & 63;
    const int wr = wave >> 1, wc = wave & 1;
    const int la = lane & 15, lkh = lane >> 4, lk = lkh * 8;

    f32x4 acc[4][4];
    #pragma unroll
    for (int i = 0; i < 4; ++i)
        #pragma unroll
        for (int j = 0; j < 4; ++j)
            acc[i][j] = (f32x4){0.f, 0.f, 0.f, 0.f};

    const int jj = tid & 127;
    const int kb = (tid >> 7) * 16;
    const int g = g0 + jj;
    const int nimg = g / SPATIAL;
    const int pos  = g % SPATIAL;
    const int oh = pos / HW, ow = pos % HW;

    for (int tap = 0; tap < 9; ++tap) {
        const int dr = tap / 3 - 1, dsx = tap % 3 - 1;
        const int ih = oh + dr, iw = ow + dsx;
        const bool valid = ((unsigned)ih < HW) && ((unsigned)iw < HW);
        const float* src = in + ((nimg * C_IN) * HW + ih) * HW + iw;
        for (int c0 = 0; c0 < C_IN; c0 += 32) {
            #pragma unroll
            for (int i = 0; i < 2; ++i) {
                const int ch = tid * 2 + i;
                const int row = ch >> 2;
                const int kp = (ch & 3) * 8;
                ushort8 v;
                #pragma unroll
                for (int e = 0; e < 8; ++e)
                    v[e] = f2bf(wraw[((m0 + row) * C_IN + c0 + kp + e) * 9 + tap]);
                *reinterpret_cast<ushort8*>(&lA[row * LDK + kp]) = v;
            }
            {
                ushort8 v0, v1;
                #pragma unroll
                for (int i = 0; i < 8; ++i)
                    v0[i] = f2bf(valid ? src[(c0 + kb + i) * SPATIAL] : 0.f);
                #pragma unroll
                for (int i = 0; i < 8; ++i)
                    v1[i] = f2bf(valid ? src[(c0 + kb + 8 + i) * SPATIAL] : 0.f);
                *reinterpret_cast<ushort8*>(&lB[jj * LDK + kb])     = v0;
                *reinterpret_cast<ushort8*>(&lB[jj * LDK + kb + 8]) = v1;
            }
            __syncthreads();
            bf16x8 af[4], bv[4];
            #pragma unroll
            for (int f = 0; f < 4; ++f) {
                af[f] = *reinterpret_cast<const bf16x8*>(&lA[(wr * 64 + f * 16 + la) * LDK + lk]);
                bv[f] = *reinterpret_cast<const bf16x8*>(&lB[(wc * 64 + f * 16 + la) * LDK + lk]);
            }
            #pragma unroll
            for (int fi = 0; fi < 4; ++fi)
                #pragma unroll
                for (int fj = 0; fj < 4; ++fj)
                    acc[fi][fj] = __builtin_amdgcn_mfma_f32_16x16x32_bf16(
                        af[fi], bv[fj], acc[fi][fj], 0, 0, 0);
            __syncthreads();
        }
    }
    const int mbase = m0 + wr * 64;
    const int cbase = g0 + wc * 64;
    #pragma unroll
    for (int fi = 0; fi < 4; ++fi) {
        float bvv[4];
        #pragma unroll
        for (int r = 0; r < 4; ++r)
            bvv[r] = bias[mbase + fi * 16 + lkh * 4 + r];
        #pragma unroll
        for (int fj = 0; fj < 4; ++fj) {
            const int gcol = cbase + fj * 16 + la;
            const int n2 = gcol / SPATIAL;
            const int p2 = gcol % SPATIAL;
            float* op = out + (size_t)(n2 * K_OUT) * SPATIAL + p2;
            #pragma unroll
            for (int r = 0; r < 4; ++r)
                op[(size_t)(mbase + fi * 16 + lkh * 4 + r) * SPATIAL] = acc[fi][fj][r] + bvv[r];
        }
    }
}

extern "C" void kernel_launch(void* const* d_in, const int* in_sizes, int n_in,
                              void* d_out, int out_size, void* d_ws, size_t ws_size,
                              hipStream_t stream) {
    const float* in   = (const float*)d_in[0];
    const float* w    = (const float*)d_in[1];
    const float* bias = (const float*)d_in[2];
    float* out = (float*)d_out;

    // ws layout (halves): pad [4*PADTOT_AL*32] | w3 [294912]
    const size_t pad_halves = 4ull * PADTOT_AL * 32ull;     // 13,779,968
    const size_t need_bytes = (pad_halves + 294912ull) * 2ull;  // ~28.15 MB

    if (ws_size >= need_bytes) {
        unsigned short* pad = (unsigned short*)d_ws;
        unsigned short* w3  = pad + pad_halves;
        border_zero<<<114, 256, 0, stream>>>(pad);
        wtrans_kernel<<<294912 / 256, 256, 0, stream>>>(w, w3);
        intrans_kernel<<<32 * HW, 256, 0, stream>>>(in, pad);
        conv_pipe<<<GEMM_N / BN, 512, 0, stream>>>(pad, w3, bias, out);
    } else {
        dim3 grid(GEMM_N / 128, K_OUT / 128);
        conv_mfma_fallback<<<grid, 256, 0, stream>>>(in, w, bias, out);
    }
}

// Round 12
// 98.210 us; speedup vs baseline: 1.4728x; 1.0218x over previous
//
#include <hip/hip_runtime.h>
#include <hip/hip_bf16.h>
#include <stdint.h>

// DenseConv2d: input (32,128,56,56) f32, weight (256,128,3,3) f32, bias (256) f32
// stride 1, pad 1 -> out (32,256,56,56) f32.
// Round 12: m201 geometry. 256x256 block tile (grid 392), 512 threads, 8 waves
// 2m x 4n (per-wave 128x64 -> 2.67 MFMA per ds_read_b128 vs 2.0 before).
// Double-buffered 2x64KB LDS staged in HALF-TILES: tile u h1 staged at u-1,
// h0 staged TWO tiles early (mid-tile barrier makes the overwrite legal) so
// the end-of-tile wait is vmcnt(4) -- never 0 in the loop (T4). af1 prefetch
// flies over MFMA0 via counted lgkmcnt(8). 32-MFMA clusters per barrier.

typedef __attribute__((ext_vector_type(8))) short bf16x8;
typedef __attribute__((ext_vector_type(8))) unsigned short ushort8;
typedef __attribute__((ext_vector_type(4))) float f32x4;

#define HW       56
#define SPATIAL  3136
#define C_IN     128
#define K_OUT    256
#define GEMM_K   1152
#define GEMM_N   100352      // 32*3136

#define PHW      58
#define PIMG     3364        // 58*58
#define PADTOT_AL 107656     // 32*3364 + 8 slack positions

#define BM       256
#define BN       256
#define NTILE    18          // K-tiles of 64 (tap = t>>1, ch-half = t&1)
#define BUFH     32768       // halves per LDS buffer: A 16384 + B 16384 (64 KiB)

__device__ __forceinline__ unsigned short f2bf(float f) {
    union { float f; unsigned int u; } v; v.f = f;
    unsigned int u = v.u + 0x7FFFu + ((v.u >> 16) & 1u);   // RTNE
    return (unsigned short)(u >> 16);
}

__device__ __forceinline__ void gload16(const unsigned short* g, unsigned short* l) {
    __builtin_amdgcn_global_load_lds(
        (const __attribute__((address_space(1))) unsigned int*)(g),
        (__attribute__((address_space(3))) unsigned int*)(l),
        16, 0, 0);
}

// weight [256][128][3][3] f32 -> w3: chunk (rc,tap,cc) = 512 halves; slot l
// (l=0..63, 8 halves) holds W[row rc*16 + (l&15)][ch cc*32 + (l>>4)*8 + j][tap].
__global__ void wtrans_kernel(const float* __restrict__ w, unsigned short* __restrict__ w3) {
    int idx = blockIdx.x * 256 + threadIdx.x;    // 294912
    int rc   = idx / 18432;
    int rem  = idx % 18432;
    int tap  = rem / 2048;
    int rem2 = rem % 2048;
    int cc   = rem2 / 512;
    int s    = rem2 % 512;
    int l    = s >> 3, j = s & 7;
    int ko   = rc * 16 + (l & 15);
    int c    = cc * 32 + ((l >> 4) << 3) + j;
    w3[idx] = f2bf(w[(ko * C_IN + c) * 9 + tap]);
}

// zero only the border ring of pad[4][32][58*58][32] (1.9 MB)
__global__ __launch_bounds__(256)
void border_zero(unsigned short* __restrict__ pad) {
    int idx = blockIdx.x * 256 + threadIdx.x;    // 4*32*228 = 29184
    if (idx >= 29184) return;
    int cc  = idx / 7296;
    int r   = idx % 7296;
    int img = r / 228;
    int p   = r % 228;
    int pos;
    if (p < 58)       pos = p;
    else if (p < 116) pos = 57 * PHW + (p - 58);
    else { int i = p - 116; pos = (1 + (i >> 1)) * PHW + (i & 1) * 57; }
    unsigned short* d = pad + (size_t)cc * PADTOT_AL * 32
                      + ((size_t)img * PIMG + pos) * 32;
    const ushort8 z = (ushort8){0,0,0,0,0,0,0,0};
    *reinterpret_cast<ushort8*>(d)      = z;
    *reinterpret_cast<ushort8*>(d + 8)  = z;
    *reinterpret_cast<ushort8*>(d + 16) = z;
    *reinterpret_cast<ushort8*>(d + 24) = z;
}

// input [32][128][56][56] f32 -> pad[4cc][32img][58*58][32ch] bf16 (interior)
__global__ __launch_bounds__(256)
void intrans_kernel(const float* __restrict__ in, unsigned short* __restrict__ pad) {
    __shared__ __attribute__((aligned(16))) unsigned short l[56 * 136];
    const int bx = blockIdx.x;                   // 32*56
    const int n = bx / HW, h = bx % HW;
    const int tid = threadIdx.x;
    const float* src = in + (size_t)n * C_IN * SPATIAL + h * HW;
    #pragma unroll
    for (int i = 0; i < 28; ++i) {               // 7168 = 28*256
        int idx = i * 256 + tid;
        int c = idx / HW, w = idx % HW;
        l[w * 136 + c] = f2bf(src[(size_t)c * SPATIAL + w]);
    }
    __syncthreads();
    const int prow = n * PIMG + (h + 1) * PHW;
    #pragma unroll
    for (int j = 0; j < 4; ++j) {
        int chunk = j * 256 + tid;               // 896 = 56*16 chunks of 8 halves
        if (chunk < 896) {
            int w = chunk >> 4, c8 = chunk & 15;
            int cc = c8 >> 2, sub = c8 & 3;
            unsigned short* dst = pad + (size_t)cc * PADTOT_AL * 32
                                + (size_t)(prow + w + 1) * 32 + sub * 8;
            *reinterpret_cast<ushort8*>(dst) =
                *reinterpret_cast<const ushort8*>(&l[w * 136 + c8 * 8]);
        }
    }
}

// ---------------- main kernel ----------------
// LDS buffer (halves): A chunks [(rc*2+kc)*512] rc=0..15; B at 16384:
// [(bc*2+kc)*512] bc=0..15. Chunk slot l = (row/col l&15, k-gran l>>4).
__global__ __launch_bounds__(512, 2)
void conv_m256(const unsigned short* __restrict__ pad,   // [4][PADTOT_AL][32]
               const unsigned short* __restrict__ w3,    // chunked weights
               const float* __restrict__ bias,
               float* __restrict__ out) {
    __shared__ __attribute__((aligned(16))) unsigned short lds[2 * BUFH]; // 128 KiB

    const int tid  = threadIdx.x;
    const int wave = tid >> 6;          // 0..7
    const int lane = tid & 63;
    const int la   = lane & 15;
    const int lkh  = lane >> 4;

    // bijective XCD swizzle: 392 blocks = 8 * 49
    const int bid = blockIdx.x;
    const int nt  = (bid & 7) * 49 + (bid >> 3);      // 0..391
    const int g0  = nt * BN;

    const int wr = wave >> 2, wc = wave & 3;          // 2m x 4n, 128x64 tiles

    // ---- staging descriptors (wave covers rc/bc = 2*wave, 2*wave+1) ----
    const unsigned short* aw0 = w3 + (size_t)(wave * 2 + 0) * 18432 + lane * 8;
    const unsigned short* aw1 = w3 + (size_t)(wave * 2 + 1) * 18432 + lane * 8;
    const unsigned short* bsrc0;
    const unsigned short* bsrc1;
    {
        int col = g0 + (wave * 2 + 0) * 16 + la;
        int img = col / SPATIAL;
        int pos = col - img * SPATIAL;
        int oh  = pos / HW, ow = pos - oh * HW;
        bsrc0 = pad + (size_t)(img * PIMG + (oh + 1) * PHW + (ow + 1)) * 32 + lkh * 8;
        col = g0 + (wave * 2 + 1) * 16 + la;
        img = col / SPATIAL;
        pos = col - img * SPATIAL;
        oh  = pos / HW; ow = pos - oh * HW;
        bsrc1 = pad + (size_t)(img * PIMG + (oh + 1) * PHW + (ow + 1)) * 32 + lkh * 8;
    }

    f32x4 acc[8][4];
    #pragma unroll
    for (int i = 0; i < 8; ++i)
        #pragma unroll
        for (int j = 0; j < 4; ++j)
            acc[i][j] = (f32x4){0.f, 0.f, 0.f, 0.f};

    // stage half kc of tile tn into buf[tn&1]: A chunks (2w,kc),(2w+1,kc) +
    // B chunks (2w,kc),(2w+1,kc)  -> 4 gloads per wave
    auto STAGE = [&](int tn, int kc) {
        const int tap = tn >> 1;
        const int cc  = (tn & 1) * 2 + kc;            // global 32-ch chunk 0..3
        const int dr = tap / 3 - 1, dsx = tap % 3 - 1;
        unsigned short* dst = &lds[(tn & 1) * BUFH];
        const ptrdiff_t bofs = (ptrdiff_t)cc * PADTOT_AL * 32 + (dr * PHW + dsx) * 32;
        gload16(aw0 + (size_t)(tap * 4 + cc) * 512, dst + ((wave * 2 + 0) * 2 + kc) * 512);
        gload16(aw1 + (size_t)(tap * 4 + cc) * 512, dst + ((wave * 2 + 1) * 2 + kc) * 512);
        gload16(bsrc0 + bofs, dst + 16384 + ((wave * 2 + 0) * 2 + kc) * 512);
        gload16(bsrc1 + bofs, dst + 16384 + ((wave * 2 + 1) * 2 + kc) * 512);
    };

    bf16x8 af0[8], af1[8], bv0[4], bv1[4];

    // prologue: tile0 both halves + tile1 h0 (12 loads); wait tile0 -> vmcnt(4)
    STAGE(0, 0); STAGE(0, 1); STAGE(1, 0);
    asm volatile("s_waitcnt vmcnt(4)" ::: "memory");
    __builtin_amdgcn_s_barrier();

    #pragma unroll
    for (int t = 0; t < NTILE; ++t) {
        const unsigned short* Ab = &lds[(t & 1) * BUFH];

        // ---- phase ks0 ----
        #pragma unroll
        for (int mi = 0; mi < 8; ++mi)
            af0[mi] = *reinterpret_cast<const bf16x8*>(
                &Ab[((wr * 8 + mi) * 2 + 0) * 512 + lane * 8]);
        #pragma unroll
        for (int nj = 0; nj < 4; ++nj)
            bv0[nj] = *reinterpret_cast<const bf16x8*>(
                &Ab[16384 + ((wc * 4 + nj) * 2 + 0) * 512 + lane * 8]);
        // prefetch ks1 A-frags: fly over MFMA0
        #pragma unroll
        for (int mi = 0; mi < 8; ++mi)
            af1[mi] = *reinterpret_cast<const bf16x8*>(
                &Ab[((wr * 8 + mi) * 2 + 1) * 512 + lane * 8]);

        asm volatile("s_waitcnt lgkmcnt(8)" ::: "memory");  // af0+bv0 done, af1 flying
        __builtin_amdgcn_sched_barrier(0);
        __builtin_amdgcn_s_setprio(1);
        #pragma unroll
        for (int mi = 0; mi < 8; ++mi)
            #pragma unroll
            for (int nj = 0; nj < 4; ++nj)
                acc[mi][nj] = __builtin_amdgcn_mfma_f32_16x16x32_bf16(
                    af0[mi], bv0[nj], acc[mi][nj], 0, 0, 0);
        __builtin_amdgcn_s_setprio(0);

        __builtin_amdgcn_s_barrier();   // all waves' h0 reads drained (lgkm(8))

        // ---- phase ks1 ----
        #pragma unroll
        for (int nj = 0; nj < 4; ++nj)
            bv1[nj] = *reinterpret_cast<const bf16x8*>(
                &Ab[16384 + ((wc * 4 + nj) * 2 + 1) * 512 + lane * 8]);
        if (t + 1 < NTILE) STAGE(t + 1, 1);   // buf[(t+1)&1] h1: safe (own drain + barrier history)
        if (t + 2 < NTILE) STAGE(t + 2, 0);   // buf[t&1] h0: safe AFTER mid barrier

        asm volatile("s_waitcnt lgkmcnt(0)" ::: "memory");  // af1+bv1 done
        __builtin_amdgcn_sched_barrier(0);
        __builtin_amdgcn_s_setprio(1);
        #pragma unroll
        for (int mi = 0; mi < 8; ++mi)
            #pragma unroll
            for (int nj = 0; nj < 4; ++nj)
                acc[mi][nj] = __builtin_amdgcn_mfma_f32_16x16x32_bf16(
                    af1[mi], bv1[nj], acc[mi][nj], 0, 0, 0);
        __builtin_amdgcn_s_setprio(0);

        // end of tile: tile t+1 (oldest 8 loads) landed; t+2 h0 stays in flight
        if (t < NTILE - 2) {
            asm volatile("s_waitcnt vmcnt(4)" ::: "memory");
            __builtin_amdgcn_s_barrier();
        } else if (t == NTILE - 2) {
            asm volatile("s_waitcnt vmcnt(0)" ::: "memory");
            __builtin_amdgcn_s_barrier();
        }
    }

    // ---- epilogue: D col = lane&15, row = (lane>>4)*4 + reg ----
    #pragma unroll
    for (int mi = 0; mi < 8; ++mi) {
        const int mb = wr * 128 + mi * 16 + lkh * 4;
        const f32x4 bv4 = *reinterpret_cast<const f32x4*>(&bias[mb]);
        #pragma unroll
        for (int nj = 0; nj < 4; ++nj) {
            const int gcol = g0 + wc * 64 + nj * 16;   // 16-aligned: one image
            const int n2 = gcol / SPATIAL;
            const int p2 = gcol - n2 * SPATIAL + la;
            float* op = out + ((size_t)(n2 * K_OUT + mb)) * SPATIAL + p2;
            op[0]                   = acc[mi][nj][0] + bv4[0];
            op[SPATIAL]             = acc[mi][nj][1] + bv4[1];
            op[2 * SPATIAL]         = acc[mi][nj][2] + bv4[2];
            op[3 * (size_t)SPATIAL] = acc[mi][nj][3] + bv4[3];
        }
    }
}

// ---------------- fallback (round-1 path) if ws is too small ----------------
#define LDK 40
__global__ __launch_bounds__(256)
void conv_mfma_fallback(const float* __restrict__ in,
                        const float* __restrict__ wraw,
                        const float* __restrict__ bias,
                        float* __restrict__ out) {
    __shared__ __attribute__((aligned(16))) unsigned short lA[128 * LDK];
    __shared__ __attribute__((aligned(16))) unsigned short lB[128 * LDK];
    const int tid = threadIdx.x;
    const int m0  = blockIdx.y * 128;
    const int g0  = blockIdx.x * 128;
    const int wave = tid >> 6, lane = tid & 63;
    const int wr = wave >> 1, wc = wave & 1;
    const int la = lane & 15, lkh = lane >> 4, lk = lkh * 8;

    f32x4 acc[4][4];
    #pragma unroll
    for (int i = 0; i < 4; ++i)
        #pragma unroll
        for (int j = 0; j < 4; ++j)
            acc[i][j] = (f32x4){0.f, 0.f, 0.f, 0.f};

    const int jj = tid & 127;
    const int kb = (tid >> 7) * 16;
    const int g = g0 + jj;
    const int nimg = g / SPATIAL;
    const int pos  = g % SPATIAL;
    const int oh = pos / HW, ow = pos % HW;

    for (int tap = 0; tap < 9; ++tap) {
        const int dr = tap / 3 - 1, dsx = tap % 3 - 1;
        const int ih = oh + dr, iw = ow + dsx;
        const bool valid = ((unsigned)ih < HW) && ((unsigned)iw < HW);
        const float* src = in + ((nimg * C_IN) * HW + ih) * HW + iw;
        for (int c0 = 0; c0 < C_IN; c0 += 32) {
            #pragma unroll
            for (int i = 0; i < 2; ++i) {
                const int ch = tid * 2 + i;
                const int row = ch >> 2;
                const int kp = (ch & 3) * 8;
                ushort8 v;
                #pragma unroll
                for (int e = 0; e < 8; ++e)
                    v[e] = f2bf(wraw[((m0 + row) * C_IN + c0 + kp + e) * 9 + tap]);
                *reinterpret_cast<ushort8*>(&lA[row * LDK + kp]) = v;
            }
            {
                ushort8 v0, v1;
                #pragma unroll
                for (int i = 0; i < 8; ++i)
                    v0[i] = f2bf(valid ? src[(c0 + kb + i) * SPATIAL] : 0.f);
                #pragma unroll
                for (int i = 0; i < 8; ++i)
                    v1[i] = f2bf(valid ? src[(c0 + kb + 8 + i) * SPATIAL] : 0.f);
                *reinterpret_cast<ushort8*>(&lB[jj * LDK + kb])     = v0;
                *reinterpret_cast<ushort8*>(&lB[jj * LDK + kb + 8]) = v1;
            }
            __syncthreads();
            bf16x8 af[4], bv[4];
            #pragma unroll
            for (int f = 0; f < 4; ++f) {
                af[f] = *reinterpret_cast<const bf16x8*>(&lA[(wr * 64 + f * 16 + la) * LDK + lk]);
                bv[f] = *reinterpret_cast<const bf16x8*>(&lB[(wc * 64 + f * 16 + la) * LDK + lk]);
            }
            #pragma unroll
            for (int fi = 0; fi < 4; ++fi)
                #pragma unroll
                for (int fj = 0; fj < 4; ++fj)
                    acc[fi][fj] = __builtin_amdgcn_mfma_f32_16x16x32_bf16(
                        af[fi], bv[fj], acc[fi][fj], 0, 0, 0);
            __syncthreads();
        }
    }
    const int mbase = m0 + wr * 64;
    const int cbase = g0 + wc * 64;
    #pragma unroll
    for (int fi = 0; fi < 4; ++fi) {
        float bvv[4];
        #pragma unroll
        for (int r = 0; r < 4; ++r)
            bvv[r] = bias[mbase + fi * 16 + lkh * 4 + r];
        #pragma unroll
        for (int fj = 0; fj < 4; ++fj) {
            const int gcol = cbase + fj * 16 + la;
            const int n2 = gcol / SPATIAL;
            const int p2 = gcol % SPATIAL;
            float* op = out + (size_t)(n2 * K_OUT) * SPATIAL + p2;
            #pragma unroll
            for (int r = 0; r < 4; ++r)
                op[(size_t)(mbase + fi * 16 + lkh * 4 + r) * SPATIAL] = acc[fi][fj][r] + bvv[r];
        }
    }
}

extern "C" void kernel_launch(void* const* d_in, const int* in_sizes, int n_in,
                              void* d_out, int out_size, void* d_ws, size_t ws_size,
                              hipStream_t stream) {
    const float* in   = (const float*)d_in[0];
    const float* w    = (const float*)d_in[1];
    const float* bias = (const float*)d_in[2];
    float* out = (float*)d_out;

    // ws layout (halves): pad [4*PADTOT_AL*32] | w3 [294912]
    const size_t pad_halves = 4ull * PADTOT_AL * 32ull;     // 13,779,968
    const size_t need_bytes = (pad_halves + 294912ull) * 2ull;  // ~28.15 MB

    if (ws_size >= need_bytes) {
        unsigned short* pad = (unsigned short*)d_ws;
        unsigned short* w3  = pad + pad_halves;
        border_zero<<<114, 256, 0, stream>>>(pad);
        wtrans_kernel<<<294912 / 256, 256, 0, stream>>>(w, w3);
        intrans_kernel<<<32 * HW, 256, 0, stream>>>(in, pad);
        conv_m256<<<GEMM_N / BN, 512, 0, stream>>>(pad, w3, bias, out);
    } else {
        dim3 grid(GEMM_N / 128, K_OUT / 128);
        conv_mfma_fallback<<<grid, 256, 0, stream>>>(in, w, bias, out);
    }
}